// Round 13
// baseline (318.636 us; speedup 1.0000x reference)
//
#include <hip/hip_runtime.h>

#define ULL unsigned long long
typedef unsigned short ush;
typedef __attribute__((ext_vector_type(8))) short s8v;   // 8 bf16 (4 VGPRs)
typedef __attribute__((ext_vector_type(4))) float f4v;   // MFMA accumulator

// problem constants
#define BB 4
#define NP 4096
#define HH 64
#define EPSF 1e-5f

// workspace float offsets (ws is float*)
#define WH_OFF      0u           // [4][27][64][64] bf16 hi
#define WL_OFF      221184u      // lo part
#define WT_PER_CONV 110592u      // bf16 elements per conv
#define VOL0_OFF    573440u      // fp32 padded [4][18][18][18][64]
#define V0H_OFF     2066432u     // bf16 padded hi } t2 reuses this region
#define V0L_OFF     2812928u     // bf16 padded lo }
#define T1_OFF      3559424u     // fp32 [4][16][16][16][64]
#define VOL1_OFF    4608000u     // fp32 padded [4][10][10][10][64]
#define V1H_OFF     4864000u     // } t4 reuses this region
#define V1L_OFF     4992000u     // }
#define T3_OFF      5120000u     // fp32 [4][8][8][8][64]
#define STATS_OFF   5251072u     // sA[4][128], sF[128], sB[4][64]
#define CELLS_OFF   5251968u     // cellStart: 4 x 4097 ints
#define SPOS_OFF    5268368u     // sortedPos: 4 x 4096 float4
#define MW_OFF      5333904u     // mlp weights bf16 (16384 ush = 8192 f)
#define CNT_OFF     5342096u     // last-block counter (1 int)

// merged zero ranges (float4 counts)
#define ZN_V0   373248u
#define ZN_V1   64000u
#define ZN_ST   224u
#define ZN_ALL  (ZN_V0 + ZN_V1 + ZN_ST)

__device__ __forceinline__ ush f2bf(float f) {            // fp32 -> bf16 RNE
  unsigned u = __float_as_uint(f);
  return (ush)((u + 0x7FFFu + ((u >> 16) & 1u)) >> 16);
}
__device__ __forceinline__ float bf2f(ush h) { return __uint_as_float(((unsigned)h) << 16); }

__device__ __forceinline__ float gelu_tanh(float v) {
  float inner = 0.7978845608028654f * (v + 0.044715f * v * v * v);
  return 0.5f * v * (1.0f + tanhf(inner));
}

__device__ __forceinline__ float lin16(int i) {
  return -1.0f + (float)i * (2.0f / 15.0f);
}

// ------------------- fused: zero scratch + weight split (blocks>=4) + bin (blocks 0-3)
__global__ __launch_bounds__(256) void k_prepbin(const float* __restrict__ cw,
                                                 const float* __restrict__ pw2,
                                                 const float* __restrict__ upw,
                                                 const float* __restrict__ pos,
                                                 ush* __restrict__ wh,
                                                 ush* __restrict__ wl,
                                                 ush* __restrict__ mw,
                                                 float* __restrict__ ws,
                                                 int* __restrict__ cellStart,
                                                 float4* __restrict__ sortedPos) {
  __shared__ int cnt[4096];
  __shared__ int wsum[4];
  int tid = threadIdx.x;
  if (blockIdx.x < 4) {
    int b = blockIdx.x;
    const float* pb = pos + b * NP * 3;
    for (int i = tid; i < 4096; i += 256) cnt[i] = 0;
    __syncthreads();
#pragma unroll
    for (int t = 0; t < 16; ++t) {
      int p = t * 256 + tid;
      float px = pb[3 * p], py = pb[3 * p + 1], pz = pb[3 * p + 2];
      int c0 = (int)floorf((px + 1.0f) * 7.5f + 0.5f);
      int c1 = (int)floorf((py + 1.0f) * 7.5f + 0.5f);
      int c2 = (int)floorf((pz + 1.0f) * 7.5f + 0.5f);
      c0 = min(max(c0, 0), 15); c1 = min(max(c1, 0), 15); c2 = min(max(c2, 0), 15);
      atomicAdd(&cnt[(c0 * 16 + c1) * 16 + c2], 1);
    }
    __syncthreads();
    int base = tid * 16;
    int loc[16];
    int run = 0;
#pragma unroll
    for (int j = 0; j < 16; ++j) { loc[j] = run; run += cnt[base + j]; }
    int lane = tid & 63, wv = tid >> 6;
    int inc = run;
    for (int d = 1; d < 64; d <<= 1) {
      int o = __shfl_up(inc, d, 64);
      if (lane >= d) inc += o;
    }
    if (lane == 63) wsum[wv] = inc;
    __syncthreads();
    int woff = 0;
    for (int w = 0; w < wv; ++w) woff += wsum[w];
    int excl = woff + inc - run;
    __syncthreads();
    int stv[16];
#pragma unroll
    for (int j = 0; j < 16; ++j) {
      stv[j] = excl + loc[j];
      cellStart[b * 4097 + base + j] = stv[j];
    }
#pragma unroll
    for (int j = 0; j < 16; ++j) cnt[base + j] = stv[j];
    if (tid == 0) cellStart[b * 4097 + 4096] = NP;
    __syncthreads();
#pragma unroll
    for (int t = 0; t < 16; ++t) {
      int p = t * 256 + tid;
      float px = pb[3 * p], py = pb[3 * p + 1], pz = pb[3 * p + 2];
      int c0 = (int)floorf((px + 1.0f) * 7.5f + 0.5f);
      int c1 = (int)floorf((py + 1.0f) * 7.5f + 0.5f);
      int c2 = (int)floorf((pz + 1.0f) * 7.5f + 0.5f);
      c0 = min(max(c0, 0), 15); c1 = min(max(c1, 0), 15); c2 = min(max(c2, 0), 15);
      int slot = atomicAdd(&cnt[(c0 * 16 + c1) * 16 + c2], 1);
      sortedPos[b * 4096 + slot] = make_float4(px, py, pz, __int_as_float(p));
    }
  } else {
    unsigned i = (blockIdx.x - 4) * 256u + tid;
    if (blockIdx.x == 4 && tid == 0) *((int*)(ws + CNT_OFF)) = 0;
    float4 z = make_float4(0.f, 0.f, 0.f, 0.f);
    if (i < ZN_V0) ((float4*)(ws + V0H_OFF))[i] = z;
    else if (i < ZN_V0 + ZN_V1) ((float4*)(ws + V1H_OFF))[i - ZN_V0] = z;
    else if (i < ZN_ALL) ((float4*)(ws + STATS_OFF))[i - ZN_V0 - ZN_V1] = z;
    if (i < 442368u) {
      unsigned conv = i / WT_PER_CONV;
      unsigned r = i - conv * WT_PER_CONV;
      unsigned co = r / 1728u;
      unsigned r2 = r - co * 1728u;
      unsigned ci = r2 / 27u;
      unsigned off = r2 - ci * 27u;
      float w = cw[i];
      ush hi = f2bf(w);
      unsigned dst = conv * WT_PER_CONV + (off * 64u + co) * 64u + ci;
      wh[dst] = hi;
      wl[dst] = f2bf(w - bf2f(hi));
    } else if (i < 450560u) {
      unsigned t = i - 442368u;
      unsigned mat = t >> 12, r = t & 4095u;
      unsigned co = r >> 6, ci = r & 63u;
      const float* src = mat ? upw : pw2;
      float w = src[ci * 64u + co];
      ush hi = f2bf(w);
      mw[mat * 8192u + co * 64u + ci] = hi;
      mw[mat * 8192u + 4096u + co * 64u + ci] = f2bf(w - bf2f(hi));
    }
  }
}

// ---------------------- subgroup helpers (16-lane KNN)
__device__ __forceinline__ void ins8(ULL* kk, ULL key) {
  if (key < kk[7]) {
    kk[7] = key;
#pragma unroll
    for (int q = 7; q >= 1; --q) {
      ULL a = kk[q - 1], c = kk[q];
      bool sw = c < a;
      kk[q - 1] = sw ? c : a;
      kk[q] = sw ? a : c;
    }
  }
}
// merge 16 lanes' sorted top-8 -> lane sub (<8) of the 16-group holds rank-sub.
__device__ __forceinline__ ULL merge16(ULL* kk, int sub) {
  ULL win = ~0ULL;
#pragma unroll
  for (int r = 0; r < 8; ++r) {
    ULL m = kk[0];
#pragma unroll
    for (int s = 1; s < 16; s <<= 1) {           // strides stay within 16-group
      ULL o = __shfl_xor(m, s, 64);
      m = (o < m) ? o : m;
    }
    if (kk[0] == m) {                            // equal keys pop together (dedup)
#pragma unroll
      for (int q = 0; q < 7; ++q) kk[q] = kk[q + 1];
      kk[7] = ~0ULL;
    }
    if (sub == r) win = m;
  }
  return win;
}
__device__ __forceinline__ ULL mkkey(float4 c, float gx, float gy, float gz, float gn) {
  float pn = c.x * c.x + c.y * c.y + c.z * c.z;
  float dt = gx * c.x + gy * c.y + gz * c.z;
  float d = (gn + pn) - 2.0f * dt;               // mirror reference formula
  unsigned u = __float_as_uint(d);
  u ^= (unsigned)((int)u >> 31) | 0x80000000u;
  return ((ULL)u << 32) | (unsigned)__float_as_uint(c.w);
}
__device__ __forceinline__ void scan_cell(const int* __restrict__ cs,
                                          const float4* __restrict__ sp,
                                          int cell, float gx, float gy, float gz,
                                          float gn, ULL* kk) {
  int st = cs[cell], en = cs[cell + 1];
  for (int p = st; p < en; ++p) ins8(kk, mkkey(sp[p], gx, gy, gz, gn));
}

// -------------- fused exact-KNN (z-column tile, 16 lanes/voxel) + MLP via MFMA.
// Block = one (b, x, y) column of 16 voxels. Phase 1: stage all points of the
// column's radius-3 x/y cell box (7x7x16 cells ~ 784 pts) into LDS; 16 lanes
// per voxel scan + merge16; per-voxel cert bound from clipped box (z spans the
// whole domain -> no z constraint; unclipped x/y faces >= 4 cells -> 3.5h);
// fallbacks: radius-5 global scan (5.5h) -> full scan (provably exact).
// Phase 2: original mlp2 body; neighbor idx read from LDS (no global round-trip).
__global__ __launch_bounds__(256) void k_knnmlp(
    const int* __restrict__ cellStart, const float4* __restrict__ sortedPos,
    const float* __restrict__ pos, const float* __restrict__ xf,
    const float* __restrict__ w1, const float* __restrict__ b1,
    const float* __restrict__ b2v, const float* __restrict__ fw,
    const float* __restrict__ fb, const float* __restrict__ ub,
    const ush* __restrict__ w2tH, const ush* __restrict__ w2tL,
    const ush* __restrict__ uwtH, const ush* __restrict__ uwtL,
    float* __restrict__ vol0, ush* __restrict__ v0h, ush* __restrict__ v0l) {
  __shared__ __align__(16) unsigned char smem[80384];
  __shared__ int lidx[128];
  // mlp-phase carving
  ush* lhH = (ush*)smem;                                  // 128*72 ush
  ush* lhL = lhH + 128 * 72;
  float* lfe = (float*)(lhL + 128 * 72);                  // 128*68 f
  ush* agH = (ush*)((unsigned char*)lfe + 128 * 68 * 4);  // 16*72 ush
  ush* agL = agH + 16 * 72;
  float* gpb = (float*)(agL + 16 * 72);                   // 128*8 f
  // knn-phase aliases (dead before mlp arrays are written)
  float4* pts = (float4*)smem;                            // 1024*16 B
  int* rst = (int*)(smem + 16384);
  int* rlen = rst + 64;
  int* rof = rlen + 64;
  int* Tsh = rof + 64;
  int tid = threadIdx.x, lane = tid & 63, wv = tid >> 6;
  int lm = lane & 15, quad = lane >> 4;
  int b = blockIdx.x >> 8;
  int g0 = (blockIdx.x & 255) << 4;
  int xc = g0 >> 8, yc = (g0 >> 4) & 15;
  // ---- phase 1: KNN for the 16-voxel z-column (xc, yc) ----
  int sub = tid & 15;
  int vz = tid >> 4;                                      // voxel z in [0,16)
  float gx = lin16(xc), gy = lin16(yc), gz = lin16(vz);
  float gn = gx * gx + gy * gy + gz * gz;
  const int* cs = cellStart + b * 4097;
  const float4* sp = sortedPos + b * 4096;
  int loa = max(xc - 3, 0), hia = min(xc + 3, 15);
  int lob = max(yc - 3, 0), hib = min(yc + 3, 15);
  int Ra = hia - loa + 1, Rb = hib - lob + 1;
  int nrows = Ra * Rb;                                    // <= 49
  if (tid < 64) {
    int st = 0, len = 0;
    if (tid < nrows) {
      int a = loa + tid / Rb, c1 = lob + tid % Rb;
      int base = (a * 16 + c1) * 16;                      // full z column of cells
      st = cs[base];
      len = cs[base + 16] - st;
    }
    rst[tid] = st;
    rlen[tid] = len;
    int s0 = len;
    for (int d = 1; d < 64; d <<= 1) { int o = __shfl_up(s0, d, 64); if (lane >= d) s0 += o; }
    rof[tid] = s0 - len;
    if (tid == 63) *Tsh = s0;
  }
  __syncthreads();
  int T = *Tsh;
  if (T <= 1024) {
    for (int i = tid; i < T; i += 256) {                  // coalesced row-wise copy
      int lo = 0, hi = nrows - 1;
      while (lo < hi) { int mid = (lo + hi + 1) >> 1; if (rof[mid] <= i) lo = mid; else hi = mid - 1; }
      pts[i] = sp[rst[lo] + (i - rof[lo])];
    }
  }
  __syncthreads();
  ULL kk[8];
#pragma unroll
  for (int q = 0; q < 8; ++q) kk[q] = ~0ULL;
  if (T <= 1024) {
    int i = sub;
    for (; i + 16 < T; i += 32) {                         // 2 LDS reads in flight
      float4 c0 = pts[i];
      float4 c1 = pts[i + 16];
      ULL k0 = mkkey(c0, gx, gy, gz, gn);
      ULL k1 = mkkey(c1, gx, gy, gz, gn);
      ins8(kk, k0);
      ins8(kk, k1);
    }
    for (; i < T; i += 16) ins8(kk, mkkey(pts[i], gx, gy, gz, gn));
  }
  ULL win = merge16(kk, sub);
  ULL w7 = __shfl(win, (lane & 48) | 7, 64);              // subgroup's rank-7 key
  int dmin = 100;                                         // z: no constraint (full span)
  if (loa > 0)  dmin = min(dmin, xc - loa + 1);
  if (hia < 15) dmin = min(dmin, hia + 1 - xc);
  if (lob > 0)  dmin = min(dmin, yc - lob + 1);
  if (hib < 15) dmin = min(dmin, yc >= 0 ? hib + 1 - yc : 100);
  float bnd = ((float)dmin - 0.5f) * (2.0f / 15.0f) - 1e-5f;
  ULL ubk = ((ULL)(__float_as_uint(bnd * bnd) | 0x80000000u)) << 32;
  if (w7 >= ubk) {
    // ---- stage 2: radius-5 box, fresh global scan ----
#pragma unroll
    for (int q = 0; q < 8; ++q) kk[q] = ~0ULL;
    for (int t = sub; t < 1331; t += 16) {
      int dz = t / 121, r = t - dz * 121;
      int a = xc + dz - 5, c1 = yc + (r / 11) - 5, c2 = vz + (r % 11) - 5;
      if (((unsigned)a > 15u) | ((unsigned)c1 > 15u) | ((unsigned)c2 > 15u)) continue;
      scan_cell(cs, sp, (a * 16 + c1) * 16 + c2, gx, gy, gz, gn, kk);
    }
    win = merge16(kk, sub);
    float bnd5 = 5.5f * (2.0f / 15.0f) - 1e-5f;
    ULL ub5 = ((ULL)(__float_as_uint(bnd5 * bnd5) | 0x80000000u)) << 32;
    w7 = __shfl(win, (lane & 48) | 7, 64);
    if (w7 >= ub5) {
      // ---- stage 3: full scan (exactness guard) ----
#pragma unroll
      for (int q = 0; q < 8; ++q) kk[q] = ~0ULL;
      for (int p = sub; p < NP; p += 16) ins8(kk, mkkey(sp[p], gx, gy, gz, gn));
      win = merge16(kk, sub);
    }
  }
  if (sub < 8) lidx[vz * 8 + sub] = (int)(win & 0xFFFFFFFFULL);
  __syncthreads();                                        // pts region dead after this
  // ---- phase 2: MLP (B-frags preload, gather via lidx, GEMMs) ----
  s8v BH[8], BL[8], UH[2], UL[2];
#pragma unroll
  for (int n = 0; n < 4; ++n)
#pragma unroll
    for (int ks = 0; ks < 2; ++ks) {
      int o = ((n * 16 + lm) << 6) + ks * 32 + (quad << 3);
      BH[n * 2 + ks] = *(const s8v*)(w2tH + o);
      BL[n * 2 + ks] = *(const s8v*)(w2tL + o);
    }
#pragma unroll
  for (int ks = 0; ks < 2; ++ks) {
    int o = ((wv * 16 + lm) << 6) + ks * 32 + (quad << 3);
    UH[ks] = *(const s8v*)(uwtH + o);
    UL[ks] = *(const s8v*)(uwtL + o);
  }
  if (tid < 128) {
    int p = lidx[tid];                                    // vi = tid>>3, kp = tid&7
    const float* pp = pos + (b * NP + p) * 3;
    const float* xp = xf + (b * NP + p) * 3;
    gpb[tid * 8 + 0] = pp[0]; gpb[tid * 8 + 1] = pp[1]; gpb[tid * 8 + 2] = pp[2];
    gpb[tid * 8 + 3] = xp[0]; gpb[tid * 8 + 4] = xp[1]; gpb[tid * 8 + 5] = xp[2];
  }
  float w10 = w1[lane], w11 = w1[64 + lane], w12 = w1[128 + lane], b1c = b1[lane];
  float fw0 = fw[lane], fw1 = fw[64 + lane], fw2 = fw[128 + lane], fbc = fb[lane];
  float ubc = ub[wv * 16 + lm];
  __syncthreads();
  for (int i = 0; i < 32; ++i) {
    int pair = wv * 32 + i;
    int vi = pair >> 3;
    float gzz = lin16(vi);
    float r0 = gpb[pair * 8 + 0] - gx, r1 = gpb[pair * 8 + 1] - gy, r2 = gpb[pair * 8 + 2] - gzz;
    float h1 = gelu_tanh(fmaf(r2, w12, fmaf(r1, w11, fmaf(r0, w10, b1c))));
    float fe = fmaf(gpb[pair * 8 + 5], fw2,
                    fmaf(gpb[pair * 8 + 4], fw1, fmaf(gpb[pair * 8 + 3], fw0, fbc)));
    ush hi = f2bf(h1);
    lhH[pair * 72 + lane] = hi;
    lhL[pair * 72 + lane] = f2bf(h1 - bf2f(hi));
    lfe[pair * 68 + lane] = fe;
  }
  f4v acc[2][4];
#pragma unroll
  for (int m = 0; m < 2; ++m)
#pragma unroll
    for (int n = 0; n < 4; ++n) acc[m][n] = (f4v){0.f, 0.f, 0.f, 0.f};
#pragma unroll
  for (int m = 0; m < 2; ++m)
#pragma unroll
    for (int ks = 0; ks < 2; ++ks) {
      int ao = (wv * 32 + m * 16 + lm) * 72 + ks * 32 + quad * 8;
      s8v Ah = *(const s8v*)&lhH[ao];
      s8v Al = *(const s8v*)&lhL[ao];
#pragma unroll
      for (int n = 0; n < 4; ++n) {
        acc[m][n] = __builtin_amdgcn_mfma_f32_16x16x32_bf16(Ah, BH[n * 2 + ks], acc[m][n], 0, 0, 0);
        acc[m][n] = __builtin_amdgcn_mfma_f32_16x16x32_bf16(Ah, BL[n * 2 + ks], acc[m][n], 0, 0, 0);
        acc[m][n] = __builtin_amdgcn_mfma_f32_16x16x32_bf16(Al, BH[n * 2 + ks], acc[m][n], 0, 0, 0);
      }
    }
  float b2c[4];
#pragma unroll
  for (int n = 0; n < 4; ++n) b2c[n] = b2v[n * 16 + lm];
#pragma unroll
  for (int m = 0; m < 2; ++m) {
    int vox = wv * 4 + m * 2 + (quad >> 1);
#pragma unroll
    for (int n = 0; n < 4; ++n) {
      float s = 0.0f;
#pragma unroll
      for (int r = 0; r < 4; ++r) {
        int pair = wv * 32 + m * 16 + quad * 4 + r;
        s += (acc[m][n][r] + b2c[n]) * lfe[pair * 68 + n * 16 + lm];
      }
      s += __shfl_xor(s, 16, 64);
      s *= 0.125f;
      if ((quad & 1) == 0) {
        ush hi = f2bf(s);
        agH[vox * 72 + n * 16 + lm] = hi;
        agL[vox * 72 + n * 16 + lm] = f2bf(s - bf2f(hi));
      }
    }
  }
  __syncthreads();
  f4v a2 = (f4v){0.f, 0.f, 0.f, 0.f};
#pragma unroll
  for (int ks = 0; ks < 2; ++ks) {
    int ao = lm * 72 + ks * 32 + quad * 8;
    s8v Ah = *(const s8v*)&agH[ao];
    s8v Al = *(const s8v*)&agL[ao];
    a2 = __builtin_amdgcn_mfma_f32_16x16x32_bf16(Ah, UH[ks], a2, 0, 0, 0);
    a2 = __builtin_amdgcn_mfma_f32_16x16x32_bf16(Ah, UL[ks], a2, 0, 0, 0);
    a2 = __builtin_amdgcn_mfma_f32_16x16x32_bf16(Al, UH[ks], a2, 0, 0, 0);
  }
#pragma unroll
  for (int r = 0; r < 4; ++r) {
    int vox = quad * 4 + r;                               // == z coordinate
    float h = gelu_tanh(a2[r] + ubc);
    int pidx = (((b * 18 + vox + 1) * 18 + yc + 1) * 18 + xc + 1) * 64 + wv * 16 + lm;
    vol0[pidx] = h;
    ush hi = f2bf(h);
    v0h[pidx] = hi;
    v0l[pidx] = f2bf(h - bf2f(hi));
  }
}

// ------------- MFMA implicit-GEMM 3x3x3 conv, 64 voxels/block, B-prefetch.
// FUSED=1: stage from fp32 t + BN stats (fused bn+relu+bf16-split); FUSED=0:
// stage from pre-split bf16 hi/lo padded volume.
template <int Z, int FUSED>
__global__ __launch_bounds__(256) void k_convm(const ush* __restrict__ vh,
                                               const ush* __restrict__ vl,
                                               const float* __restrict__ tin,
                                               const float* __restrict__ instats,
                                               float inv_cnt,
                                               const ush* __restrict__ wtH,
                                               const ush* __restrict__ wtL,
                                               float* __restrict__ out,
                                               float* __restrict__ stats) {
  constexpr int P = Z + 2;
  constexpr int Py = (Z == 16) ? 6 : 10;
  constexpr int Px = (Z == 16) ? 18 : 10;
  constexpr int NV = 3 * Py * Px;              // 324 / 300
  constexpr int VS = 272;
  __shared__ unsigned char slab[NV * VS];
  __shared__ float ls[64], ls2[64];
  int tid = threadIdx.x;
  int lane = tid & 63, wv = tid >> 6;
  int vbase = blockIdx.x * 64;
  int b = (Z == 16) ? (vbase >> 12) : (vbase >> 9);
  int rem = vbase & (Z * Z * Z - 1);
  int z0 = rem / (Z * Z);
  int y0 = (Z == 16) ? ((rem & 255) >> 4) : 0;
  if (tid < 64) { ls[tid] = 0.0f; ls2[tid] = 0.0f; }
  if (FUSED) {
    float mreg[8], rreg[8];
    int cb = (tid & 7) * 8;
#pragma unroll
    for (int e = 0; e < 8; ++e) {
      float sm = instats[(cb + e) * 2];
      float sq = instats[(cb + e) * 2 + 1];
      float m = sm * inv_cnt;
      float var = sq * inv_cnt - m * m;
      mreg[e] = m;
      rreg[e] = 1.0f / sqrtf(var + EPSF);
    }
    for (int i = tid; i < NV * 8; i += 256) {
      int v = i >> 3, c = i & 7;
      int lz = v / (Py * Px);
      int r = v - lz * (Py * Px);
      int ly = r / Px, lx = r - ly * Px;
      int rz = z0 + lz - 1, ry = y0 + ly - 1, rx = lx - 1;
      bool ok = ((unsigned)rz < (unsigned)Z) & ((unsigned)ry < (unsigned)Z) &
                ((unsigned)rx < (unsigned)Z);
      float vv[8];
#pragma unroll
      for (int e = 0; e < 8; ++e) vv[e] = 0.0f;
      if (ok) {
        const float* tp = tin + ((((b * Z + rz) * Z + ry) * Z + rx) << 6) + c * 8;
        float4 f0 = *(const float4*)tp;
        float4 f1 = *(const float4*)(tp + 4);
        vv[0] = f0.x; vv[1] = f0.y; vv[2] = f0.z; vv[3] = f0.w;
        vv[4] = f1.x; vv[5] = f1.y; vv[6] = f1.z; vv[7] = f1.w;
      }
      union { ush u[8]; uint4 q; } ph, pq;
#pragma unroll
      for (int e = 0; e < 8; ++e) {
        float x = (vv[e] - mreg[e]) * rreg[e];
        x = (ok && x > 0.0f) ? x : 0.0f;
        ush h = f2bf(x);
        ph.u[e] = h;
        pq.u[e] = f2bf(x - bf2f(h));
      }
      *(uint4*)(slab + v * VS + c * 16) = ph.q;
      *(uint4*)(slab + v * VS + 128 + c * 16) = pq.q;
    }
  } else {
    for (int i = tid; i < NV * 8; i += 256) {
      int v = i >> 3, c = i & 7;
      int lz = v / (Py * Px);
      int r = v - lz * (Py * Px);
      int ly = r / Px, lx = r - ly * Px;
      int g = (((b * P + z0 + lz) * P + (y0 + ly)) * P + lx) * 64 + c * 8;
      *(uint4*)(slab + v * VS + c * 16)       = *(const uint4*)(vh + g);
      *(uint4*)(slab + v * VS + 128 + c * 16) = *(const uint4*)(vl + g);
    }
  }
  __syncthreads();
  int lm = lane & 15, quad = lane >> 4;
  int co = (wv << 4) | lm;
  const ush* bH = wtH + (co << 6) + (quad << 3);   // off stride = 4096 ush
  const ush* bL = wtL + (co << 6) + (quad << 3);
  s8v cH0 = *(const s8v*)(bH), cH1 = *(const s8v*)(bH + 32);
  s8v cL0 = *(const s8v*)(bL), cL1 = *(const s8v*)(bL + 32);
  f4v acc[4];
#pragma unroll
  for (int m = 0; m < 4; ++m) acc[m] = (f4v){0.f, 0.f, 0.f, 0.f};
  for (int off = 0; off < 27; ++off) {
    int noff = (off < 26) ? off + 1 : 26;          // prefetch next B-frags
    const ush* nbH = bH + noff * 4096;
    const ush* nbL = bL + noff * 4096;
    s8v nH0 = *(const s8v*)(nbH), nH1 = *(const s8v*)(nbH + 32);
    s8v nL0 = *(const s8v*)(nbL), nL1 = *(const s8v*)(nbL + 32);
    int dz = off / 9, r9 = off - dz * 9, dy = r9 / 3, dx = r9 - dy * 3;
#pragma unroll
    for (int ks = 0; ks < 2; ++ks) {
      s8v bhf = ks ? cH1 : cH0;
      s8v blf = ks ? cL1 : cL0;
#pragma unroll
      for (int m = 0; m < 4; ++m) {
        int lyp, lxp;
        if (Z == 16) { lyp = m + dy; lxp = lm + dx; }
        else         { lyp = 2 * m + (lm >> 3) + dy; lxp = (lm & 7) + dx; }
        int sv = (dz * Py + lyp) * Px + lxp;
        const unsigned char* ap = slab + sv * VS + (quad << 4) + (ks << 6);
        s8v ahf = *(const s8v*)(ap);
        s8v alf = *(const s8v*)(ap + 128);
        acc[m] = __builtin_amdgcn_mfma_f32_16x16x32_bf16(ahf, bhf, acc[m], 0, 0, 0);
        acc[m] = __builtin_amdgcn_mfma_f32_16x16x32_bf16(ahf, blf, acc[m], 0, 0, 0);
        acc[m] = __builtin_amdgcn_mfma_f32_16x16x32_bf16(alf, bhf, acc[m], 0, 0, 0);
      }
    }
    cH0 = nH0; cH1 = nH1; cL0 = nL0; cL1 = nL1;
  }
  float s = 0.0f, s2 = 0.0f;
#pragma unroll
  for (int m = 0; m < 4; ++m) {
    int vx = vbase + (m << 4) + (quad << 2);
#pragma unroll
    for (int r = 0; r < 4; ++r) {
      float v = acc[m][r];
      out[(vx + r) * 64 + co] = v;
      s += v;
      s2 = fmaf(v, v, s2);
    }
  }
  atomicAdd(&ls[co], s);
  atomicAdd(&ls2[co], s2);
  __syncthreads();
  if (tid < 64) {
    atomicAdd(&stats[tid * 2], ls[tid]);
    atomicAdd(&stats[tid * 2 + 1], ls2[tid]);
  }
}

// --------------------------------- vol = relu(vol0 + bn(t2)) then 2x2x2 maxpool
__global__ __launch_bounds__(256) void k_residpool(const float* __restrict__ vol0,
                                                   const float* __restrict__ t2,
                                                   const float* __restrict__ stats,
                                                   float* __restrict__ vol1,
                                                   ush* __restrict__ v1h,
                                                   ush* __restrict__ v1l) {
  unsigned i = blockIdx.x * 256u + threadIdx.x;
  int c = i & 63;
  int pv = i >> 6;
  int xp = pv & 7, yp = (pv >> 3) & 7, zp = (pv >> 6) & 7, b = pv >> 9;
  float m = stats[c * 2] * (1.0f / 16384.0f);
  float var = stats[c * 2 + 1] * (1.0f / 16384.0f) - m * m;
  float rs = 1.0f / sqrtf(var + EPSF);
  float best = 0.0f;
  for (int dz = 0; dz < 2; ++dz)
    for (int dy = 0; dy < 2; ++dy)
      for (int dx = 0; dx < 2; ++dx) {
        int z = 2 * zp + dz, y = 2 * yp + dy, x = 2 * xp + dx;
        float a = vol0[(((b * 18 + z + 1) * 18 + y + 1) * 18 + x + 1) * 64 + c];
        float t = t2[(b * 4096 + z * 256 + y * 16 + x) * 64 + c];
        float u = a + (t - m) * rs;
        u = u > 0.0f ? u : 0.0f;
        best = u > best ? u : best;
      }
  int pidx = (((b * 10 + zp + 1) * 10 + yp + 1) * 10 + xp + 1) * 64 + c;
  vol1[pidx] = best;
  ush hi = f2bf(best);
  v1h[pidx] = hi;
  v1l[pidx] = f2bf(best - bf2f(hi));
}

// ----- vol2 = relu(vol1 + bn(t4)) stats; LAST block also computes the head.
__global__ __launch_bounds__(256) void k_resid2f(const float* __restrict__ vol1,
                                                 const float* __restrict__ t4,
                                                 const float* __restrict__ stats,
                                                 float* __restrict__ sF,
                                                 float* __restrict__ sB,
                                                 int* __restrict__ cnt,
                                                 const float* __restrict__ ong,
                                                 const float* __restrict__ onb,
                                                 const float* __restrict__ row,
                                                 const float* __restrict__ rob,
                                                 float* __restrict__ outp) {
  __shared__ float ls[64], ls2[64];
  __shared__ float pl[4][64];
  __shared__ int lastf;
  int tid = threadIdx.x;
  if (tid < 64) { ls[tid] = 0.0f; ls2[tid] = 0.0f; }
  __syncthreads();
  unsigned i = blockIdx.x * 256u + tid;
  int c = i & 63;
  int pv = i >> 6;
  int x = pv & 7, y = (pv >> 3) & 7, z = (pv >> 6) & 7, b = pv >> 9;
  float m = stats[c * 2] * (1.0f / 2048.0f);
  float var = stats[c * 2 + 1] * (1.0f / 2048.0f) - m * m;
  float rs = 1.0f / sqrtf(var + EPSF);
  float a = vol1[(((b * 10 + z + 1) * 10 + y + 1) * 10 + x + 1) * 64 + c];
  float u = a + (t4[i] - m) * rs;
  u = u > 0.0f ? u : 0.0f;
  atomicAdd(&ls[c], u);
  atomicAdd(&ls2[c], u * u);
  __syncthreads();
  if (tid < 64) {
    atomicAdd(&sF[tid * 2], ls[tid]);
    atomicAdd(&sF[tid * 2 + 1], ls2[tid]);
    atomicAdd(&sB[b * 64 + tid], ls[tid]);
  }
  __threadfence();                               // drain this block's atomics to L2
  __syncthreads();
  if (tid == 0) lastf = (atomicAdd(cnt, 1) == 511);
  __syncthreads();
  if (lastf) {                                   // all 512 blocks' atomics visible
    if (tid < 64) {
      int cc = tid;
      float sfm = atomicAdd(&sF[cc * 2], 0.0f);  // L2-coherent reads
      float sfq = atomicAdd(&sF[cc * 2 + 1], 0.0f);
      float mm = sfm * (1.0f / 2048.0f);
      float vv = sfq * (1.0f / 2048.0f) - mm * mm;
      float rr = 1.0f / sqrtf(vv + EPSF);
      float gg = ong[cc], bb2 = onb[cc];
      for (int bb = 0; bb < 4; ++bb) {
        float sb = atomicAdd(&sB[bb * 64 + cc], 0.0f);
        pl[bb][cc] = (sb * (1.0f / 512.0f) - mm) * rr * gg + bb2;
      }
    }
    __syncthreads();
    if (tid < 64) {
      int bb = tid >> 4, o = tid & 15;
      float s = rob[o];
      for (int j = 0; j < 64; ++j) s = fmaf(pl[bb][j], row[j * 16 + o], s);
      outp[bb * 16 + o] = s;
    }
  }
}

extern "C" void kernel_launch(void* const* d_in, const int* in_sizes, int n_in,
                              void* d_out, int out_size, void* d_ws, size_t ws_size,
                              hipStream_t stream) {
  (void)in_sizes; (void)n_in; (void)out_size; (void)ws_size;
  const float* pos = (const float*)d_in[0];
  const float* xf  = (const float*)d_in[1];
  const float* pw1 = (const float*)d_in[2];
  const float* pb1 = (const float*)d_in[3];
  const float* pw2 = (const float*)d_in[4];
  const float* pb2 = (const float*)d_in[5];
  const float* fw  = (const float*)d_in[6];
  const float* fb  = (const float*)d_in[7];
  const float* uw  = (const float*)d_in[8];
  const float* ubp = (const float*)d_in[9];
  const float* cw  = (const float*)d_in[10];
  // d_in[11] = conv_b: unused (training-mode BN cancels conv bias exactly)
  const float* ong = (const float*)d_in[12];
  const float* onb = (const float*)d_in[13];
  const float* row = (const float*)d_in[14];
  const float* rob = (const float*)d_in[15];

  float* ws   = (float*)d_ws;
  ush*   wh   = (ush*)(ws + WH_OFF);
  ush*   wl   = (ush*)(ws + WL_OFF);
  float* vol0 = ws + VOL0_OFF;
  ush*   v0h  = (ush*)(ws + V0H_OFF);
  ush*   v0l  = (ush*)(ws + V0L_OFF);
  float* t1   = ws + T1_OFF;
  float* t2   = ws + V0H_OFF;          // reuses v0h/v0l region (consumed by conv1)
  float* vol1 = ws + VOL1_OFF;
  ush*   v1h  = (ush*)(ws + V1H_OFF);
  ush*   v1l  = (ush*)(ws + V1L_OFF);
  float* t3   = ws + T3_OFF;
  float* t4   = ws + V1H_OFF;          // reuses v1h/v1l region (consumed by conv3)
  float* sA   = ws + STATS_OFF;
  float* sF   = sA + 512;
  float* sB   = sF + 128;
  int*   cellStart = (int*)(ws + CELLS_OFF);
  float4* sortedPos = (float4*)(ws + SPOS_OFF);
  ush*   mw   = (ush*)(ws + MW_OFF);
  int*   cnt  = (int*)(ws + CNT_OFF);

  k_prepbin<<<1764, 256, 0, stream>>>(cw, pw2, uw, pos, wh, wl, mw, ws,
                                      cellStart, sortedPos);
  k_knnmlp<<<1024, 256, 0, stream>>>(cellStart, sortedPos, pos, xf, pw1, pb1,
                                     pb2, fw, fb, ubp,
                                     mw, mw + 4096, mw + 8192, mw + 12288,
                                     vol0, v0h, v0l);
  // block 0 (16^3): conv1 (bf16 staging) -> conv2 (fused bn+relu staging from t1)
  k_convm<16, 0><<<256, 256, 0, stream>>>(v0h, v0l, nullptr, nullptr, 0.0f,
                                          wh, wl, t1, sA);
  k_convm<16, 1><<<256, 256, 0, stream>>>(nullptr, nullptr, t1, sA, 1.0f / 16384.0f,
                                          wh + WT_PER_CONV, wl + WT_PER_CONV,
                                          t2, sA + 128);
  k_residpool<<<512, 256, 0, stream>>>(vol0, t2, sA + 128, vol1, v1h, v1l);
  // block 1 (8^3): conv3 (bf16 staging) -> conv4 (fused bn+relu staging from t3)
  k_convm<8, 0><<<32, 256, 0, stream>>>(v1h, v1l, nullptr, nullptr, 0.0f,
                                        wh + 2 * WT_PER_CONV, wl + 2 * WT_PER_CONV,
                                        t3, sA + 256);
  k_convm<8, 1><<<32, 256, 0, stream>>>(nullptr, nullptr, t3, sA + 256, 1.0f / 2048.0f,
                                        wh + 3 * WT_PER_CONV, wl + 3 * WT_PER_CONV,
                                        t4, sA + 384);
  // resid2 + fused final head (last-block pattern)
  k_resid2f<<<512, 256, 0, stream>>>(vol1, t4, sA + 384, sF, sB, cnt,
                                     ong, onb, row, rob, (float*)d_out);
}

// Round 14
// 315.141 us; speedup vs baseline: 1.0111x; 1.0111x over previous
//
#include <hip/hip_runtime.h>

#define ULL unsigned long long
typedef unsigned short ush;
typedef __attribute__((ext_vector_type(8))) short s8v;   // 8 bf16 (4 VGPRs)
typedef __attribute__((ext_vector_type(4))) float f4v;   // MFMA accumulator

// problem constants
#define BB 4
#define NP 4096
#define HH 64
#define EPSF 1e-5f

// workspace float offsets (ws is float*)
#define WH_OFF      0u           // [4][27][64][64] bf16 hi
#define WL_OFF      221184u      // lo part
#define WT_PER_CONV 110592u      // bf16 elements per conv
#define IDX_OFF     442368u      // B*G*8 ints
#define VOL0_OFF    573440u      // fp32 padded [4][18][18][18][64]
#define V0H_OFF     2066432u     // bf16 padded hi } t2 reuses this region
#define V0L_OFF     2812928u     // bf16 padded lo }
#define T1_OFF      3559424u     // fp32 [4][16][16][16][64]
#define VOL1_OFF    4608000u     // fp32 padded [4][10][10][10][64]
#define V1H_OFF     4864000u     // } t4 reuses this region
#define V1L_OFF     4992000u     // }
#define T3_OFF      5120000u     // fp32 [4][8][8][8][64]
#define STATS_OFF   5251072u     // sA[4][128], sF[128], sB[4][64]
#define CELLS_OFF   5251968u     // cellStart: 4 x 4097 ints
#define SPOS_OFF    5268368u     // sortedPos: 4 x 4096 float4
#define MW_OFF      5333904u     // mlp weights bf16 (16384 ush = 8192 f)
#define CNT_OFF     5342096u     // last-block counter (1 int)

// merged zero ranges (float4 counts)
#define ZN_V0   373248u
#define ZN_V1   64000u
#define ZN_ST   224u
#define ZN_ALL  (ZN_V0 + ZN_V1 + ZN_ST)

__device__ __forceinline__ ush f2bf(float f) {            // fp32 -> bf16 RNE
  unsigned u = __float_as_uint(f);
  return (ush)((u + 0x7FFFu + ((u >> 16) & 1u)) >> 16);
}
__device__ __forceinline__ float bf2f(ush h) { return __uint_as_float(((unsigned)h) << 16); }

__device__ __forceinline__ float gelu_tanh(float v) {
  float inner = 0.7978845608028654f * (v + 0.044715f * v * v * v);
  return 0.5f * v * (1.0f + tanhf(inner));
}

__device__ __forceinline__ float lin16(int i) {
  return -1.0f + (float)i * (2.0f / 15.0f);
}

// ------------------- fused: zero scratch + weight split (blocks>=4) + bin (blocks 0-3)
__global__ __launch_bounds__(256) void k_prepbin(const float* __restrict__ cw,
                                                 const float* __restrict__ pw2,
                                                 const float* __restrict__ upw,
                                                 const float* __restrict__ pos,
                                                 ush* __restrict__ wh,
                                                 ush* __restrict__ wl,
                                                 ush* __restrict__ mw,
                                                 float* __restrict__ ws,
                                                 int* __restrict__ cellStart,
                                                 float4* __restrict__ sortedPos) {
  __shared__ int cnt[4096];
  __shared__ int wsum[4];
  int tid = threadIdx.x;
  if (blockIdx.x < 4) {
    int b = blockIdx.x;
    const float* pb = pos + b * NP * 3;
    for (int i = tid; i < 4096; i += 256) cnt[i] = 0;
    __syncthreads();
#pragma unroll
    for (int t = 0; t < 16; ++t) {
      int p = t * 256 + tid;
      float px = pb[3 * p], py = pb[3 * p + 1], pz = pb[3 * p + 2];
      int c0 = (int)floorf((px + 1.0f) * 7.5f + 0.5f);
      int c1 = (int)floorf((py + 1.0f) * 7.5f + 0.5f);
      int c2 = (int)floorf((pz + 1.0f) * 7.5f + 0.5f);
      c0 = min(max(c0, 0), 15); c1 = min(max(c1, 0), 15); c2 = min(max(c2, 0), 15);
      atomicAdd(&cnt[(c0 * 16 + c1) * 16 + c2], 1);
    }
    __syncthreads();
    int base = tid * 16;
    int loc[16];
    int run = 0;
#pragma unroll
    for (int j = 0; j < 16; ++j) { loc[j] = run; run += cnt[base + j]; }
    int lane = tid & 63, wv = tid >> 6;
    int inc = run;
    for (int d = 1; d < 64; d <<= 1) {
      int o = __shfl_up(inc, d, 64);
      if (lane >= d) inc += o;
    }
    if (lane == 63) wsum[wv] = inc;
    __syncthreads();
    int woff = 0;
    for (int w = 0; w < wv; ++w) woff += wsum[w];
    int excl = woff + inc - run;
    __syncthreads();
    int stv[16];
#pragma unroll
    for (int j = 0; j < 16; ++j) {
      stv[j] = excl + loc[j];
      cellStart[b * 4097 + base + j] = stv[j];
    }
#pragma unroll
    for (int j = 0; j < 16; ++j) cnt[base + j] = stv[j];
    if (tid == 0) cellStart[b * 4097 + 4096] = NP;
    __syncthreads();
#pragma unroll
    for (int t = 0; t < 16; ++t) {
      int p = t * 256 + tid;
      float px = pb[3 * p], py = pb[3 * p + 1], pz = pb[3 * p + 2];
      int c0 = (int)floorf((px + 1.0f) * 7.5f + 0.5f);
      int c1 = (int)floorf((py + 1.0f) * 7.5f + 0.5f);
      int c2 = (int)floorf((pz + 1.0f) * 7.5f + 0.5f);
      c0 = min(max(c0, 0), 15); c1 = min(max(c1, 0), 15); c2 = min(max(c2, 0), 15);
      int slot = atomicAdd(&cnt[(c0 * 16 + c1) * 16 + c2], 1);
      sortedPos[b * 4096 + slot] = make_float4(px, py, pz, __int_as_float(p));
    }
  } else {
    unsigned i = (blockIdx.x - 4) * 256u + tid;
    if (blockIdx.x == 4 && tid == 0) *((int*)(ws + CNT_OFF)) = 0;
    float4 z = make_float4(0.f, 0.f, 0.f, 0.f);
    if (i < ZN_V0) ((float4*)(ws + V0H_OFF))[i] = z;
    else if (i < ZN_V0 + ZN_V1) ((float4*)(ws + V1H_OFF))[i - ZN_V0] = z;
    else if (i < ZN_ALL) ((float4*)(ws + STATS_OFF))[i - ZN_V0 - ZN_V1] = z;
    if (i < 442368u) {
      unsigned conv = i / WT_PER_CONV;
      unsigned r = i - conv * WT_PER_CONV;
      unsigned co = r / 1728u;
      unsigned r2 = r - co * 1728u;
      unsigned ci = r2 / 27u;
      unsigned off = r2 - ci * 27u;
      float w = cw[i];
      ush hi = f2bf(w);
      unsigned dst = conv * WT_PER_CONV + (off * 64u + co) * 64u + ci;
      wh[dst] = hi;
      wl[dst] = f2bf(w - bf2f(hi));
    } else if (i < 450560u) {
      unsigned t = i - 442368u;
      unsigned mat = t >> 12, r = t & 4095u;
      unsigned co = r >> 6, ci = r & 63u;
      const float* src = mat ? upw : pw2;
      float w = src[ci * 64u + co];
      ush hi = f2bf(w);
      mw[mat * 8192u + co * 64u + ci] = hi;
      mw[mat * 8192u + 4096u + co * 64u + ci] = f2bf(w - bf2f(hi));
    }
  }
}

// ---------------------- subgroup helpers for 32-lane KNN
__device__ __forceinline__ void ins8(ULL* kk, ULL key) {
  if (key < kk[7]) {
    kk[7] = key;
#pragma unroll
    for (int q = 7; q >= 1; --q) {
      ULL a = kk[q - 1], c = kk[q];
      bool sw = c < a;
      kk[q - 1] = sw ? c : a;
      kk[q] = sw ? a : c;
    }
  }
}
__device__ __forceinline__ ULL merge32(ULL* kk, int sub) {
  ULL win = ~0ULL;
#pragma unroll
  for (int r = 0; r < 8; ++r) {
    ULL m = kk[0];
#pragma unroll
    for (int s = 1; s < 32; s <<= 1) {
      ULL o = __shfl_xor(m, s, 64);
      m = (o < m) ? o : m;
    }
    if (kk[0] == m) {
#pragma unroll
      for (int q = 0; q < 7; ++q) kk[q] = kk[q + 1];
      kk[7] = ~0ULL;
    }
    if (sub == r) win = m;
  }
  return win;
}
__device__ __forceinline__ ULL mkkey(float4 c, float gx, float gy, float gz, float gn) {
  float pn = c.x * c.x + c.y * c.y + c.z * c.z;
  float dt = gx * c.x + gy * c.y + gz * c.z;
  float d = (gn + pn) - 2.0f * dt;               // mirror reference formula
  unsigned u = __float_as_uint(d);
  u ^= (unsigned)((int)u >> 31) | 0x80000000u;
  return ((ULL)u << 32) | (unsigned)__float_as_uint(c.w);
}
__device__ __forceinline__ void scan_cell(const int* __restrict__ cs,
                                          const float4* __restrict__ sp,
                                          int cell, float gx, float gy, float gz,
                                          float gn, ULL* kk) {
  int st = cs[cell], en = cs[cell + 1];
  for (int p = st; p < en; ++p) ins8(kk, mkkey(sp[p], gx, gy, gz, gn));
}

// ------------------------------------------- tiled exact KNN, 32 lanes/voxel
__global__ __launch_bounds__(256) void k_knn5(const int* __restrict__ cellStart,
                                              const float4* __restrict__ sortedPos,
                                              int* __restrict__ idxo) {
  constexpr int CAP = 1024;
  __shared__ float4 pts[CAP];
  __shared__ int rst[64], rlen[64], rof[64];
  __shared__ int Tsh;
  int tid = threadIdx.x;
  int lane = tid & 63;
  int sub = tid & 31;
  int lv = tid >> 5;
  int blk = blockIdx.x;
  int b = blk >> 9;
  int t9 = blk & 511;
  int ii0 = (t9 >> 6) * 2, jj0 = ((t9 >> 3) & 7) * 2, kk0 = (t9 & 7) * 2;
  int ii = ii0 + (lv >> 2), jj = jj0 + ((lv >> 1) & 1), kkc = kk0 + (lv & 1);
  int g = (ii << 8) | (jj << 4) | kkc;
  float gx = lin16(ii), gy = lin16(jj), gz = lin16(kkc);
  float gn = gx * gx + gy * gy + gz * gz;
  const int* cs = cellStart + b * 4097;
  const float4* sp = sortedPos + b * 4096;
  int loa = max(ii0 - 3, 0), hia = min(ii0 + 4, 15);
  int lob = max(jj0 - 3, 0), hib = min(jj0 + 4, 15);
  int loc = max(kk0 - 3, 0), hic = min(kk0 + 4, 15);
  int Ra = hia - loa + 1, Rb = hib - lob + 1;
  int nrows = Ra * Rb;
  if (tid < 64) {
    int st = 0, len = 0;
    if (tid < nrows) {
      int a = loa + tid / Rb, c1 = lob + tid % Rb;
      int base = (a * 16 + c1) * 16;
      st = cs[base + loc];
      len = cs[base + hic + 1] - st;
    }
    rst[tid] = st;
    rlen[tid] = len;
    int s0 = len;
    for (int d = 1; d < 64; d <<= 1) { int o = __shfl_up(s0, d, 64); if (lane >= d) s0 += o; }
    rof[tid] = s0 - len;
    if (tid == 63) Tsh = s0;
  }
  __syncthreads();
  int T = Tsh;
  if (T <= CAP) {
    for (int i = tid; i < T; i += 256) {
      int lo = 0, hi = nrows - 1;
      while (lo < hi) { int mid = (lo + hi + 1) >> 1; if (rof[mid] <= i) lo = mid; else hi = mid - 1; }
      pts[i] = sp[rst[lo] + (i - rof[lo])];
    }
  }
  __syncthreads();
  ULL kk[8];
#pragma unroll
  for (int q = 0; q < 8; ++q) kk[q] = ~0ULL;
  if (T <= CAP) {
    int i = sub;
    for (; i + 32 < T; i += 64) {
      float4 c0 = pts[i];
      float4 c1 = pts[i + 32];
      ULL k0 = mkkey(c0, gx, gy, gz, gn);
      ULL k1 = mkkey(c1, gx, gy, gz, gn);
      ins8(kk, k0);
      ins8(kk, k1);
    }
    for (; i < T; i += 32) ins8(kk, mkkey(pts[i], gx, gy, gz, gn));
  }
  ULL win = merge32(kk, sub);
  ULL w7 = __shfl(win, (lane & 32) | 7, 64);
  int dmin = 100;
  if (loa > 0)  dmin = min(dmin, ii - loa + 1);
  if (hia < 15) dmin = min(dmin, hia + 1 - ii);
  if (lob > 0)  dmin = min(dmin, jj - lob + 1);
  if (hib < 15) dmin = min(dmin, hib + 1 - jj);
  if (loc > 0)  dmin = min(dmin, kkc - loc + 1);
  if (hic < 15) dmin = min(dmin, hic + 1 - kkc);
  float bnd = ((float)dmin - 0.5f) * (2.0f / 15.0f) - 1e-5f;
  ULL ubk = ((ULL)(__float_as_uint(bnd * bnd) | 0x80000000u)) << 32;
  if (w7 >= ubk) {
#pragma unroll
    for (int q = 0; q < 8; ++q) kk[q] = ~0ULL;
    for (int t = sub; t < 1331; t += 32) {
      int dz = t / 121, r = t - dz * 121;
      int a = ii + dz - 5, c1 = jj + (r / 11) - 5, c2 = kkc + (r % 11) - 5;
      if (((unsigned)a > 15u) | ((unsigned)c1 > 15u) | ((unsigned)c2 > 15u)) continue;
      scan_cell(cs, sp, (a * 16 + c1) * 16 + c2, gx, gy, gz, gn, kk);
    }
    win = merge32(kk, sub);
    float bnd5 = 5.5f * (2.0f / 15.0f) - 1e-5f;
    ULL ub5 = ((ULL)(__float_as_uint(bnd5 * bnd5) | 0x80000000u)) << 32;
    w7 = __shfl(win, (lane & 32) | 7, 64);
    if (w7 >= ub5) {
#pragma unroll
      for (int q = 0; q < 8; ++q) kk[q] = ~0ULL;
      for (int p = sub; p < NP; p += 32) ins8(kk, mkkey(sp[p], gx, gy, gz, gn));
      win = merge32(kk, sub);
    }
  }
  if (sub < 8) idxo[(((b << 12) | g) << 3) + sub] = (int)(win & 0xFFFFFFFFULL);
}

// ------------------------- fused bipartite conv + update MLP via MFMA (bf16x3)
__global__ __launch_bounds__(256) void k_mlp2(
    const float* __restrict__ pos, const float* __restrict__ xf,
    const float* __restrict__ w1, const float* __restrict__ b1,
    const float* __restrict__ b2v, const float* __restrict__ fw,
    const float* __restrict__ fb, const float* __restrict__ ub,
    const ush* __restrict__ w2tH, const ush* __restrict__ w2tL,
    const ush* __restrict__ uwtH, const ush* __restrict__ uwtL,
    const int* __restrict__ idx, float* __restrict__ vol0,
    ush* __restrict__ v0h, ush* __restrict__ v0l) {
  __shared__ __align__(16) ush lhH[128 * 72];
  __shared__ __align__(16) ush lhL[128 * 72];
  __shared__ __align__(16) float lfe[128 * 68];
  __shared__ __align__(16) ush agH[16 * 72];
  __shared__ __align__(16) ush agL[16 * 72];
  __shared__ float gpb[128 * 8];
  int tid = threadIdx.x, lane = tid & 63, wv = tid >> 6;
  int lm = lane & 15, quad = lane >> 4;
  int b = blockIdx.x >> 8;
  int g0 = (blockIdx.x & 255) << 4;
  s8v BH[8], BL[8], UH[2], UL[2];
#pragma unroll
  for (int n = 0; n < 4; ++n)
#pragma unroll
    for (int ks = 0; ks < 2; ++ks) {
      int o = ((n * 16 + lm) << 6) + ks * 32 + (quad << 3);
      BH[n * 2 + ks] = *(const s8v*)(w2tH + o);
      BL[n * 2 + ks] = *(const s8v*)(w2tL + o);
    }
#pragma unroll
  for (int ks = 0; ks < 2; ++ks) {
    int o = ((wv * 16 + lm) << 6) + ks * 32 + (quad << 3);
    UH[ks] = *(const s8v*)(uwtH + o);
    UL[ks] = *(const s8v*)(uwtL + o);
  }
  if (tid < 128) {
    int vi = tid >> 3, kp = tid & 7;
    int g = g0 + vi;
    int p = idx[(((b << 12) | g) << 3) + kp];
    const float* pp = pos + (b * NP + p) * 3;
    const float* xp = xf + (b * NP + p) * 3;
    gpb[tid * 8 + 0] = pp[0]; gpb[tid * 8 + 1] = pp[1]; gpb[tid * 8 + 2] = pp[2];
    gpb[tid * 8 + 3] = xp[0]; gpb[tid * 8 + 4] = xp[1]; gpb[tid * 8 + 5] = xp[2];
  }
  float w10 = w1[lane], w11 = w1[64 + lane], w12 = w1[128 + lane], b1c = b1[lane];
  float fw0 = fw[lane], fw1 = fw[64 + lane], fw2 = fw[128 + lane], fbc = fb[lane];
  float ubc = ub[wv * 16 + lm];
  float gx = lin16(g0 >> 8), gy = lin16((g0 >> 4) & 15);
  __syncthreads();
  for (int i = 0; i < 32; ++i) {
    int pair = wv * 32 + i;
    int vi = pair >> 3;
    float gz = lin16(vi);
    float r0 = gpb[pair * 8 + 0] - gx, r1 = gpb[pair * 8 + 1] - gy, r2 = gpb[pair * 8 + 2] - gz;
    float h1 = gelu_tanh(fmaf(r2, w12, fmaf(r1, w11, fmaf(r0, w10, b1c))));
    float fe = fmaf(gpb[pair * 8 + 5], fw2,
                    fmaf(gpb[pair * 8 + 4], fw1, fmaf(gpb[pair * 8 + 3], fw0, fbc)));
    ush hi = f2bf(h1);
    lhH[pair * 72 + lane] = hi;
    lhL[pair * 72 + lane] = f2bf(h1 - bf2f(hi));
    lfe[pair * 68 + lane] = fe;
  }
  f4v acc[2][4];
#pragma unroll
  for (int m = 0; m < 2; ++m)
#pragma unroll
    for (int n = 0; n < 4; ++n) acc[m][n] = (f4v){0.f, 0.f, 0.f, 0.f};
#pragma unroll
  for (int m = 0; m < 2; ++m)
#pragma unroll
    for (int ks = 0; ks < 2; ++ks) {
      int ao = (wv * 32 + m * 16 + lm) * 72 + ks * 32 + quad * 8;
      s8v Ah = *(const s8v*)&lhH[ao];
      s8v Al = *(const s8v*)&lhL[ao];
#pragma unroll
      for (int n = 0; n < 4; ++n) {
        acc[m][n] = __builtin_amdgcn_mfma_f32_16x16x32_bf16(Ah, BH[n * 2 + ks], acc[m][n], 0, 0, 0);
        acc[m][n] = __builtin_amdgcn_mfma_f32_16x16x32_bf16(Ah, BL[n * 2 + ks], acc[m][n], 0, 0, 0);
        acc[m][n] = __builtin_amdgcn_mfma_f32_16x16x32_bf16(Al, BH[n * 2 + ks], acc[m][n], 0, 0, 0);
      }
    }
  float b2c[4];
#pragma unroll
  for (int n = 0; n < 4; ++n) b2c[n] = b2v[n * 16 + lm];
#pragma unroll
  for (int m = 0; m < 2; ++m) {
    int vox = wv * 4 + m * 2 + (quad >> 1);
#pragma unroll
    for (int n = 0; n < 4; ++n) {
      float s = 0.0f;
#pragma unroll
      for (int r = 0; r < 4; ++r) {
        int pair = wv * 32 + m * 16 + quad * 4 + r;
        s += (acc[m][n][r] + b2c[n]) * lfe[pair * 68 + n * 16 + lm];
      }
      s += __shfl_xor(s, 16, 64);
      s *= 0.125f;
      if ((quad & 1) == 0) {
        ush hi = f2bf(s);
        agH[vox * 72 + n * 16 + lm] = hi;
        agL[vox * 72 + n * 16 + lm] = f2bf(s - bf2f(hi));
      }
    }
  }
  __syncthreads();
  f4v a2 = (f4v){0.f, 0.f, 0.f, 0.f};
#pragma unroll
  for (int ks = 0; ks < 2; ++ks) {
    int ao = lm * 72 + ks * 32 + quad * 8;
    s8v Ah = *(const s8v*)&agH[ao];
    s8v Al = *(const s8v*)&agL[ao];
    a2 = __builtin_amdgcn_mfma_f32_16x16x32_bf16(Ah, UH[ks], a2, 0, 0, 0);
    a2 = __builtin_amdgcn_mfma_f32_16x16x32_bf16(Ah, UL[ks], a2, 0, 0, 0);
    a2 = __builtin_amdgcn_mfma_f32_16x16x32_bf16(Al, UH[ks], a2, 0, 0, 0);
  }
  int xc = g0 >> 8, yc = (g0 >> 4) & 15;
#pragma unroll
  for (int r = 0; r < 4; ++r) {
    int vox = quad * 4 + r;
    float h = gelu_tanh(a2[r] + ubc);
    int pidx = (((b * 18 + vox + 1) * 18 + yc + 1) * 18 + xc + 1) * 64 + wv * 16 + lm;
    vol0[pidx] = h;
    ush hi = f2bf(h);
    v0h[pidx] = hi;
    v0l[pidx] = f2bf(h - bf2f(hi));
  }
}

// ------------- MFMA implicit-GEMM 3x3x3 conv, 64 voxels/block, B-prefetch.
// FUSED=1: stage from fp32 t + BN stats (fused bn+relu+bf16-split); FUSED=0:
// stage from pre-split bf16 hi/lo padded volume.
template <int Z, int FUSED>
__global__ __launch_bounds__(256) void k_convm(const ush* __restrict__ vh,
                                               const ush* __restrict__ vl,
                                               const float* __restrict__ tin,
                                               const float* __restrict__ instats,
                                               float inv_cnt,
                                               const ush* __restrict__ wtH,
                                               const ush* __restrict__ wtL,
                                               float* __restrict__ out,
                                               float* __restrict__ stats) {
  constexpr int P = Z + 2;
  constexpr int Py = (Z == 16) ? 6 : 10;
  constexpr int Px = (Z == 16) ? 18 : 10;
  constexpr int NV = 3 * Py * Px;              // 324 / 300
  constexpr int VS = 272;
  __shared__ unsigned char slab[NV * VS];
  __shared__ float ls[64], ls2[64];
  int tid = threadIdx.x;
  int lane = tid & 63, wv = tid >> 6;
  int vbase = blockIdx.x * 64;
  int b = (Z == 16) ? (vbase >> 12) : (vbase >> 9);
  int rem = vbase & (Z * Z * Z - 1);
  int z0 = rem / (Z * Z);
  int y0 = (Z == 16) ? ((rem & 255) >> 4) : 0;
  if (tid < 64) { ls[tid] = 0.0f; ls2[tid] = 0.0f; }
  if (FUSED) {
    float mreg[8], rreg[8];
    int cb = (tid & 7) * 8;
#pragma unroll
    for (int e = 0; e < 8; ++e) {
      float sm = instats[(cb + e) * 2];
      float sq = instats[(cb + e) * 2 + 1];
      float m = sm * inv_cnt;
      float var = sq * inv_cnt - m * m;
      mreg[e] = m;
      rreg[e] = 1.0f / sqrtf(var + EPSF);
    }
    for (int i = tid; i < NV * 8; i += 256) {
      int v = i >> 3, c = i & 7;
      int lz = v / (Py * Px);
      int r = v - lz * (Py * Px);
      int ly = r / Px, lx = r - ly * Px;
      int rz = z0 + lz - 1, ry = y0 + ly - 1, rx = lx - 1;
      bool ok = ((unsigned)rz < (unsigned)Z) & ((unsigned)ry < (unsigned)Z) &
                ((unsigned)rx < (unsigned)Z);
      float vv[8];
#pragma unroll
      for (int e = 0; e < 8; ++e) vv[e] = 0.0f;
      if (ok) {
        const float* tp = tin + ((((b * Z + rz) * Z + ry) * Z + rx) << 6) + c * 8;
        float4 f0 = *(const float4*)tp;
        float4 f1 = *(const float4*)(tp + 4);
        vv[0] = f0.x; vv[1] = f0.y; vv[2] = f0.z; vv[3] = f0.w;
        vv[4] = f1.x; vv[5] = f1.y; vv[6] = f1.z; vv[7] = f1.w;
      }
      union { ush u[8]; uint4 q; } ph, pq;
#pragma unroll
      for (int e = 0; e < 8; ++e) {
        float x = (vv[e] - mreg[e]) * rreg[e];
        x = (ok && x > 0.0f) ? x : 0.0f;
        ush h = f2bf(x);
        ph.u[e] = h;
        pq.u[e] = f2bf(x - bf2f(h));
      }
      *(uint4*)(slab + v * VS + c * 16) = ph.q;
      *(uint4*)(slab + v * VS + 128 + c * 16) = pq.q;
    }
  } else {
    for (int i = tid; i < NV * 8; i += 256) {
      int v = i >> 3, c = i & 7;
      int lz = v / (Py * Px);
      int r = v - lz * (Py * Px);
      int ly = r / Px, lx = r - ly * Px;
      int g = (((b * P + z0 + lz) * P + (y0 + ly)) * P + lx) * 64 + c * 8;
      *(uint4*)(slab + v * VS + c * 16)       = *(const uint4*)(vh + g);
      *(uint4*)(slab + v * VS + 128 + c * 16) = *(const uint4*)(vl + g);
    }
  }
  __syncthreads();
  int lm = lane & 15, quad = lane >> 4;
  int co = (wv << 4) | lm;
  const ush* bH = wtH + (co << 6) + (quad << 3);   // off stride = 4096 ush
  const ush* bL = wtL + (co << 6) + (quad << 3);
  s8v cH0 = *(const s8v*)(bH), cH1 = *(const s8v*)(bH + 32);
  s8v cL0 = *(const s8v*)(bL), cL1 = *(const s8v*)(bL + 32);
  f4v acc[4];
#pragma unroll
  for (int m = 0; m < 4; ++m) acc[m] = (f4v){0.f, 0.f, 0.f, 0.f};
  for (int off = 0; off < 27; ++off) {
    int noff = (off < 26) ? off + 1 : 26;          // prefetch next B-frags
    const ush* nbH = bH + noff * 4096;
    const ush* nbL = bL + noff * 4096;
    s8v nH0 = *(const s8v*)(nbH), nH1 = *(const s8v*)(nbH + 32);
    s8v nL0 = *(const s8v*)(nbL), nL1 = *(const s8v*)(nbL + 32);
    int dz = off / 9, r9 = off - dz * 9, dy = r9 / 3, dx = r9 - dy * 3;
#pragma unroll
    for (int ks = 0; ks < 2; ++ks) {
      s8v bhf = ks ? cH1 : cH0;
      s8v blf = ks ? cL1 : cL0;
#pragma unroll
      for (int m = 0; m < 4; ++m) {
        int lyp, lxp;
        if (Z == 16) { lyp = m + dy; lxp = lm + dx; }
        else         { lyp = 2 * m + (lm >> 3) + dy; lxp = (lm & 7) + dx; }
        int sv = (dz * Py + lyp) * Px + lxp;
        const unsigned char* ap = slab + sv * VS + (quad << 4) + (ks << 6);
        s8v ahf = *(const s8v*)(ap);
        s8v alf = *(const s8v*)(ap + 128);
        acc[m] = __builtin_amdgcn_mfma_f32_16x16x32_bf16(ahf, bhf, acc[m], 0, 0, 0);
        acc[m] = __builtin_amdgcn_mfma_f32_16x16x32_bf16(ahf, blf, acc[m], 0, 0, 0);
        acc[m] = __builtin_amdgcn_mfma_f32_16x16x32_bf16(alf, bhf, acc[m], 0, 0, 0);
      }
    }
    cH0 = nH0; cH1 = nH1; cL0 = nL0; cL1 = nL1;
  }
  float s = 0.0f, s2 = 0.0f;
#pragma unroll
  for (int m = 0; m < 4; ++m) {
    int vx = vbase + (m << 4) + (quad << 2);
#pragma unroll
    for (int r = 0; r < 4; ++r) {
      float v = acc[m][r];
      out[(vx + r) * 64 + co] = v;
      s += v;
      s2 = fmaf(v, v, s2);
    }
  }
  atomicAdd(&ls[co], s);
  atomicAdd(&ls2[co], s2);
  __syncthreads();
  if (tid < 64) {
    atomicAdd(&stats[tid * 2], ls[tid]);
    atomicAdd(&stats[tid * 2 + 1], ls2[tid]);
  }
}

// --------------------------------- vol = relu(vol0 + bn(t2)) then 2x2x2 maxpool
__global__ __launch_bounds__(256) void k_residpool(const float* __restrict__ vol0,
                                                   const float* __restrict__ t2,
                                                   const float* __restrict__ stats,
                                                   float* __restrict__ vol1,
                                                   ush* __restrict__ v1h,
                                                   ush* __restrict__ v1l) {
  unsigned i = blockIdx.x * 256u + threadIdx.x;
  int c = i & 63;
  int pv = i >> 6;
  int xp = pv & 7, yp = (pv >> 3) & 7, zp = (pv >> 6) & 7, b = pv >> 9;
  float m = stats[c * 2] * (1.0f / 16384.0f);
  float var = stats[c * 2 + 1] * (1.0f / 16384.0f) - m * m;
  float rs = 1.0f / sqrtf(var + EPSF);
  float best = 0.0f;
  for (int dz = 0; dz < 2; ++dz)
    for (int dy = 0; dy < 2; ++dy)
      for (int dx = 0; dx < 2; ++dx) {
        int z = 2 * zp + dz, y = 2 * yp + dy, x = 2 * xp + dx;
        float a = vol0[(((b * 18 + z + 1) * 18 + y + 1) * 18 + x + 1) * 64 + c];
        float t = t2[(b * 4096 + z * 256 + y * 16 + x) * 64 + c];
        float u = a + (t - m) * rs;
        u = u > 0.0f ? u : 0.0f;
        best = u > best ? u : best;
      }
  int pidx = (((b * 10 + zp + 1) * 10 + yp + 1) * 10 + xp + 1) * 64 + c;
  vol1[pidx] = best;
  ush hi = f2bf(best);
  v1h[pidx] = hi;
  v1l[pidx] = f2bf(best - bf2f(hi));
}

// ----- vol2 = relu(vol1 + bn(t4)) stats; LAST block also computes the head.
__global__ __launch_bounds__(256) void k_resid2f(const float* __restrict__ vol1,
                                                 const float* __restrict__ t4,
                                                 const float* __restrict__ stats,
                                                 float* __restrict__ sF,
                                                 float* __restrict__ sB,
                                                 int* __restrict__ cnt,
                                                 const float* __restrict__ ong,
                                                 const float* __restrict__ onb,
                                                 const float* __restrict__ row,
                                                 const float* __restrict__ rob,
                                                 float* __restrict__ outp) {
  __shared__ float ls[64], ls2[64];
  __shared__ float pl[4][64];
  __shared__ int lastf;
  int tid = threadIdx.x;
  if (tid < 64) { ls[tid] = 0.0f; ls2[tid] = 0.0f; }
  __syncthreads();
  unsigned i = blockIdx.x * 256u + tid;
  int c = i & 63;
  int pv = i >> 6;
  int x = pv & 7, y = (pv >> 3) & 7, z = (pv >> 6) & 7, b = pv >> 9;
  float m = stats[c * 2] * (1.0f / 2048.0f);
  float var = stats[c * 2 + 1] * (1.0f / 2048.0f) - m * m;
  float rs = 1.0f / sqrtf(var + EPSF);
  float a = vol1[(((b * 10 + z + 1) * 10 + y + 1) * 10 + x + 1) * 64 + c];
  float u = a + (t4[i] - m) * rs;
  u = u > 0.0f ? u : 0.0f;
  atomicAdd(&ls[c], u);
  atomicAdd(&ls2[c], u * u);
  __syncthreads();
  if (tid < 64) {
    atomicAdd(&sF[tid * 2], ls[tid]);
    atomicAdd(&sF[tid * 2 + 1], ls2[tid]);
    atomicAdd(&sB[b * 64 + tid], ls[tid]);
  }
  __threadfence();                               // drain this block's atomics to L2
  __syncthreads();
  if (tid == 0) lastf = (atomicAdd(cnt, 1) == 511);
  __syncthreads();
  if (lastf) {                                   // all 512 blocks' atomics visible
    if (tid < 64) {
      int cc = tid;
      float sfm = atomicAdd(&sF[cc * 2], 0.0f);  // L2-coherent reads
      float sfq = atomicAdd(&sF[cc * 2 + 1], 0.0f);
      float mm = sfm * (1.0f / 2048.0f);
      float vv = sfq * (1.0f / 2048.0f) - mm * mm;
      float rr = 1.0f / sqrtf(vv + EPSF);
      float gg = ong[cc], bb2 = onb[cc];
      for (int bb = 0; bb < 4; ++bb) {
        float sb = atomicAdd(&sB[bb * 64 + cc], 0.0f);
        pl[bb][cc] = (sb * (1.0f / 512.0f) - mm) * rr * gg + bb2;
      }
    }
    __syncthreads();
    if (tid < 64) {
      int bb = tid >> 4, o = tid & 15;
      float s = rob[o];
      for (int j = 0; j < 64; ++j) s = fmaf(pl[bb][j], row[j * 16 + o], s);
      outp[bb * 16 + o] = s;
    }
  }
}

extern "C" void kernel_launch(void* const* d_in, const int* in_sizes, int n_in,
                              void* d_out, int out_size, void* d_ws, size_t ws_size,
                              hipStream_t stream) {
  (void)in_sizes; (void)n_in; (void)out_size; (void)ws_size;
  const float* pos = (const float*)d_in[0];
  const float* xf  = (const float*)d_in[1];
  const float* pw1 = (const float*)d_in[2];
  const float* pb1 = (const float*)d_in[3];
  const float* pw2 = (const float*)d_in[4];
  const float* pb2 = (const float*)d_in[5];
  const float* fw  = (const float*)d_in[6];
  const float* fb  = (const float*)d_in[7];
  const float* uw  = (const float*)d_in[8];
  const float* ubp = (const float*)d_in[9];
  const float* cw  = (const float*)d_in[10];
  // d_in[11] = conv_b: unused (training-mode BN cancels conv bias exactly)
  const float* ong = (const float*)d_in[12];
  const float* onb = (const float*)d_in[13];
  const float* row = (const float*)d_in[14];
  const float* rob = (const float*)d_in[15];

  float* ws   = (float*)d_ws;
  ush*   wh   = (ush*)(ws + WH_OFF);
  ush*   wl   = (ush*)(ws + WL_OFF);
  int*   idx  = (int*)(ws + IDX_OFF);
  float* vol0 = ws + VOL0_OFF;
  ush*   v0h  = (ush*)(ws + V0H_OFF);
  ush*   v0l  = (ush*)(ws + V0L_OFF);
  float* t1   = ws + T1_OFF;
  float* t2   = ws + V0H_OFF;          // reuses v0h/v0l region (consumed by conv1)
  float* vol1 = ws + VOL1_OFF;
  ush*   v1h  = (ush*)(ws + V1H_OFF);
  ush*   v1l  = (ush*)(ws + V1L_OFF);
  float* t3   = ws + T3_OFF;
  float* t4   = ws + V1H_OFF;          // reuses v1h/v1l region (consumed by conv3)
  float* sA   = ws + STATS_OFF;
  float* sF   = sA + 512;
  float* sB   = sF + 128;
  int*   cellStart = (int*)(ws + CELLS_OFF);
  float4* sortedPos = (float4*)(ws + SPOS_OFF);
  ush*   mw   = (ush*)(ws + MW_OFF);
  int*   cnt  = (int*)(ws + CNT_OFF);

  k_prepbin<<<1764, 256, 0, stream>>>(cw, pw2, uw, pos, wh, wl, mw, ws,
                                      cellStart, sortedPos);
  k_knn5<<<2048, 256, 0, stream>>>(cellStart, sortedPos, idx);
  k_mlp2<<<1024, 256, 0, stream>>>(pos, xf, pw1, pb1, pb2, fw, fb, ubp,
                                   mw, mw + 4096, mw + 8192, mw + 12288,
                                   idx, vol0, v0h, v0l);
  // block 0 (16^3): conv1 (bf16 staging) -> conv2 (fused bn+relu staging from t1)
  k_convm<16, 0><<<256, 256, 0, stream>>>(v0h, v0l, nullptr, nullptr, 0.0f,
                                          wh, wl, t1, sA);
  k_convm<16, 1><<<256, 256, 0, stream>>>(nullptr, nullptr, t1, sA, 1.0f / 16384.0f,
                                          wh + WT_PER_CONV, wl + WT_PER_CONV,
                                          t2, sA + 128);
  k_residpool<<<512, 256, 0, stream>>>(vol0, t2, sA + 128, vol1, v1h, v1l);
  // block 1 (8^3): conv3 (bf16 staging) -> conv4 (fused bn+relu staging from t3)
  k_convm<8, 0><<<32, 256, 0, stream>>>(v1h, v1l, nullptr, nullptr, 0.0f,
                                        wh + 2 * WT_PER_CONV, wl + 2 * WT_PER_CONV,
                                        t3, sA + 256);
  k_convm<8, 1><<<32, 256, 0, stream>>>(nullptr, nullptr, t3, sA + 256, 1.0f / 2048.0f,
                                        wh + 3 * WT_PER_CONV, wl + 3 * WT_PER_CONV,
                                        t4, sA + 384);
  // resid2 + fused final head (last-block pattern)
  k_resid2f<<<512, 256, 0, stream>>>(vol1, t4, sA + 384, sF, sB, cnt,
                                     ong, onb, row, rob, (float*)d_out);
}

// Round 15
// 294.453 us; speedup vs baseline: 1.0821x; 1.0703x over previous
//
#include <hip/hip_runtime.h>

#define ULL unsigned long long
typedef unsigned short ush;
typedef __attribute__((ext_vector_type(8))) short s8v;   // 8 bf16 (4 VGPRs)
typedef __attribute__((ext_vector_type(4))) float f4v;   // MFMA accumulator

// problem constants
#define BB 4
#define NP 4096
#define HH 64
#define EPSF 1e-5f

// workspace float offsets (ws is float*)
#define WH_OFF      0u           // [4][27][64][64] bf16 hi
#define WL_OFF      221184u      // lo part
#define WT_PER_CONV 110592u      // bf16 elements per conv
#define IDX_OFF     442368u      // B*G*8 ints
#define VOL0_OFF    573440u      // fp32 padded [4][18][18][18][64]
#define V0H_OFF     2066432u     // bf16 padded hi } t2 reuses this region
#define V0L_OFF     2812928u     // bf16 padded lo }
#define T1_OFF      3559424u     // fp32 [4][16][16][16][64]
#define VOL1_OFF    4608000u     // fp32 padded [4][10][10][10][64]
#define V1H_OFF     4864000u     // } t4 reuses this region
#define V1L_OFF     4992000u     // }
#define T3_OFF      5120000u     // fp32 [4][8][8][8][64]
#define STATS_OFF   5251072u     // sA[4][128], sF[128], sB[4][64]
#define CELLS_OFF   5251968u     // cellStart: 4 x 4097 ints
#define SPOS_OFF    5268368u     // sortedPos: 4 x 4096 float4
#define MW_OFF      5333904u     // mlp weights bf16 (16384 ush = 8192 f)

// merged zero ranges (float4 counts)
#define ZN_V0   373248u
#define ZN_V1   64000u
#define ZN_ST   224u
#define ZN_ALL  (ZN_V0 + ZN_V1 + ZN_ST)

__device__ __forceinline__ ush f2bf(float f) {            // fp32 -> bf16 RNE
  unsigned u = __float_as_uint(f);
  return (ush)((u + 0x7FFFu + ((u >> 16) & 1u)) >> 16);
}
__device__ __forceinline__ float bf2f(ush h) { return __uint_as_float(((unsigned)h) << 16); }

__device__ __forceinline__ float gelu_tanh(float v) {
  float inner = 0.7978845608028654f * (v + 0.044715f * v * v * v);
  return 0.5f * v * (1.0f + tanhf(inner));
}

__device__ __forceinline__ float lin16(int i) {
  return -1.0f + (float)i * (2.0f / 15.0f);
}

// ------------------- fused: zero scratch + weight split (blocks>=4) + bin (blocks 0-3)
__global__ __launch_bounds__(256) void k_prepbin(const float* __restrict__ cw,
                                                 const float* __restrict__ pw2,
                                                 const float* __restrict__ upw,
                                                 const float* __restrict__ pos,
                                                 ush* __restrict__ wh,
                                                 ush* __restrict__ wl,
                                                 ush* __restrict__ mw,
                                                 float* __restrict__ ws,
                                                 int* __restrict__ cellStart,
                                                 float4* __restrict__ sortedPos) {
  __shared__ int cnt[4096];
  __shared__ int wsum[4];
  int tid = threadIdx.x;
  if (blockIdx.x < 4) {
    int b = blockIdx.x;
    const float* pb = pos + b * NP * 3;
    for (int i = tid; i < 4096; i += 256) cnt[i] = 0;
    __syncthreads();
#pragma unroll
    for (int t = 0; t < 16; ++t) {
      int p = t * 256 + tid;
      float px = pb[3 * p], py = pb[3 * p + 1], pz = pb[3 * p + 2];
      int c0 = (int)floorf((px + 1.0f) * 7.5f + 0.5f);
      int c1 = (int)floorf((py + 1.0f) * 7.5f + 0.5f);
      int c2 = (int)floorf((pz + 1.0f) * 7.5f + 0.5f);
      c0 = min(max(c0, 0), 15); c1 = min(max(c1, 0), 15); c2 = min(max(c2, 0), 15);
      atomicAdd(&cnt[(c0 * 16 + c1) * 16 + c2], 1);
    }
    __syncthreads();
    int base = tid * 16;
    int loc[16];
    int run = 0;
#pragma unroll
    for (int j = 0; j < 16; ++j) { loc[j] = run; run += cnt[base + j]; }
    int lane = tid & 63, wv = tid >> 6;
    int inc = run;
    for (int d = 1; d < 64; d <<= 1) {
      int o = __shfl_up(inc, d, 64);
      if (lane >= d) inc += o;
    }
    if (lane == 63) wsum[wv] = inc;
    __syncthreads();
    int woff = 0;
    for (int w = 0; w < wv; ++w) woff += wsum[w];
    int excl = woff + inc - run;
    __syncthreads();
    int stv[16];
#pragma unroll
    for (int j = 0; j < 16; ++j) {
      stv[j] = excl + loc[j];
      cellStart[b * 4097 + base + j] = stv[j];
    }
#pragma unroll
    for (int j = 0; j < 16; ++j) cnt[base + j] = stv[j];
    if (tid == 0) cellStart[b * 4097 + 4096] = NP;
    __syncthreads();
#pragma unroll
    for (int t = 0; t < 16; ++t) {
      int p = t * 256 + tid;
      float px = pb[3 * p], py = pb[3 * p + 1], pz = pb[3 * p + 2];
      int c0 = (int)floorf((px + 1.0f) * 7.5f + 0.5f);
      int c1 = (int)floorf((py + 1.0f) * 7.5f + 0.5f);
      int c2 = (int)floorf((pz + 1.0f) * 7.5f + 0.5f);
      c0 = min(max(c0, 0), 15); c1 = min(max(c1, 0), 15); c2 = min(max(c2, 0), 15);
      int slot = atomicAdd(&cnt[(c0 * 16 + c1) * 16 + c2], 1);
      sortedPos[b * 4096 + slot] = make_float4(px, py, pz, __int_as_float(p));
    }
  } else {
    unsigned i = (blockIdx.x - 4) * 256u + tid;
    float4 z = make_float4(0.f, 0.f, 0.f, 0.f);
    if (i < ZN_V0) ((float4*)(ws + V0H_OFF))[i] = z;
    else if (i < ZN_V0 + ZN_V1) ((float4*)(ws + V1H_OFF))[i - ZN_V0] = z;
    else if (i < ZN_ALL) ((float4*)(ws + STATS_OFF))[i - ZN_V0 - ZN_V1] = z;
    if (i < 442368u) {
      unsigned conv = i / WT_PER_CONV;
      unsigned r = i - conv * WT_PER_CONV;
      unsigned co = r / 1728u;
      unsigned r2 = r - co * 1728u;
      unsigned ci = r2 / 27u;
      unsigned off = r2 - ci * 27u;
      float w = cw[i];
      ush hi = f2bf(w);
      unsigned dst = conv * WT_PER_CONV + (off * 64u + co) * 64u + ci;
      wh[dst] = hi;
      wl[dst] = f2bf(w - bf2f(hi));
    } else if (i < 450560u) {
      unsigned t = i - 442368u;
      unsigned mat = t >> 12, r = t & 4095u;
      unsigned co = r >> 6, ci = r & 63u;
      const float* src = mat ? upw : pw2;
      float w = src[ci * 64u + co];
      ush hi = f2bf(w);
      mw[mat * 8192u + co * 64u + ci] = hi;
      mw[mat * 8192u + 4096u + co * 64u + ci] = f2bf(w - bf2f(hi));
    }
  }
}

// ---------------------- subgroup helpers for 32-lane KNN
__device__ __forceinline__ void ins8(ULL* kk, ULL key) {
  if (key < kk[7]) {
    kk[7] = key;
#pragma unroll
    for (int q = 7; q >= 1; --q) {
      ULL a = kk[q - 1], c = kk[q];
      bool sw = c < a;
      kk[q - 1] = sw ? c : a;
      kk[q] = sw ? a : c;
    }
  }
}
__device__ __forceinline__ ULL merge32(ULL* kk, int sub) {
  ULL win = ~0ULL;
#pragma unroll
  for (int r = 0; r < 8; ++r) {
    ULL m = kk[0];
#pragma unroll
    for (int s = 1; s < 32; s <<= 1) {
      ULL o = __shfl_xor(m, s, 64);
      m = (o < m) ? o : m;
    }
    if (kk[0] == m) {
#pragma unroll
      for (int q = 0; q < 7; ++q) kk[q] = kk[q + 1];
      kk[7] = ~0ULL;
    }
    if (sub == r) win = m;
  }
  return win;
}
__device__ __forceinline__ ULL mkkey(float4 c, float gx, float gy, float gz, float gn) {
  float pn = c.x * c.x + c.y * c.y + c.z * c.z;
  float dt = gx * c.x + gy * c.y + gz * c.z;
  float d = (gn + pn) - 2.0f * dt;               // mirror reference formula
  unsigned u = __float_as_uint(d);
  u ^= (unsigned)((int)u >> 31) | 0x80000000u;
  return ((ULL)u << 32) | (unsigned)__float_as_uint(c.w);
}
__device__ __forceinline__ void scan_cell(const int* __restrict__ cs,
                                          const float4* __restrict__ sp,
                                          int cell, float gx, float gy, float gz,
                                          float gn, ULL* kk) {
  int st = cs[cell], en = cs[cell + 1];
  for (int p = st; p < en; ++p) ins8(kk, mkkey(sp[p], gx, gy, gz, gn));
}

// ------------------------------------------- tiled exact KNN, 32 lanes/voxel
__global__ __launch_bounds__(256) void k_knn5(const int* __restrict__ cellStart,
                                              const float4* __restrict__ sortedPos,
                                              int* __restrict__ idxo) {
  constexpr int CAP = 1024;
  __shared__ float4 pts[CAP];
  __shared__ int rst[64], rlen[64], rof[64];
  __shared__ int Tsh;
  int tid = threadIdx.x;
  int lane = tid & 63;
  int sub = tid & 31;
  int lv = tid >> 5;
  int blk = blockIdx.x;
  int b = blk >> 9;
  int t9 = blk & 511;
  int ii0 = (t9 >> 6) * 2, jj0 = ((t9 >> 3) & 7) * 2, kk0 = (t9 & 7) * 2;
  int ii = ii0 + (lv >> 2), jj = jj0 + ((lv >> 1) & 1), kkc = kk0 + (lv & 1);
  int g = (ii << 8) | (jj << 4) | kkc;
  float gx = lin16(ii), gy = lin16(jj), gz = lin16(kkc);
  float gn = gx * gx + gy * gy + gz * gz;
  const int* cs = cellStart + b * 4097;
  const float4* sp = sortedPos + b * 4096;
  int loa = max(ii0 - 3, 0), hia = min(ii0 + 4, 15);
  int lob = max(jj0 - 3, 0), hib = min(jj0 + 4, 15);
  int loc = max(kk0 - 3, 0), hic = min(kk0 + 4, 15);
  int Ra = hia - loa + 1, Rb = hib - lob + 1;
  int nrows = Ra * Rb;
  if (tid < 64) {
    int st = 0, len = 0;
    if (tid < nrows) {
      int a = loa + tid / Rb, c1 = lob + tid % Rb;
      int base = (a * 16 + c1) * 16;
      st = cs[base + loc];
      len = cs[base + hic + 1] - st;
    }
    rst[tid] = st;
    rlen[tid] = len;
    int s0 = len;
    for (int d = 1; d < 64; d <<= 1) { int o = __shfl_up(s0, d, 64); if (lane >= d) s0 += o; }
    rof[tid] = s0 - len;
    if (tid == 63) Tsh = s0;
  }
  __syncthreads();
  int T = Tsh;
  if (T <= CAP) {
    for (int i = tid; i < T; i += 256) {
      int lo = 0, hi = nrows - 1;
      while (lo < hi) { int mid = (lo + hi + 1) >> 1; if (rof[mid] <= i) lo = mid; else hi = mid - 1; }
      pts[i] = sp[rst[lo] + (i - rof[lo])];
    }
  }
  __syncthreads();
  ULL kk[8];
#pragma unroll
  for (int q = 0; q < 8; ++q) kk[q] = ~0ULL;
  if (T <= CAP) {
    int i = sub;
    for (; i + 32 < T; i += 64) {
      float4 c0 = pts[i];
      float4 c1 = pts[i + 32];
      ULL k0 = mkkey(c0, gx, gy, gz, gn);
      ULL k1 = mkkey(c1, gx, gy, gz, gn);
      ins8(kk, k0);
      ins8(kk, k1);
    }
    for (; i < T; i += 32) ins8(kk, mkkey(pts[i], gx, gy, gz, gn));
  }
  ULL win = merge32(kk, sub);
  ULL w7 = __shfl(win, (lane & 32) | 7, 64);
  int dmin = 100;
  if (loa > 0)  dmin = min(dmin, ii - loa + 1);
  if (hia < 15) dmin = min(dmin, hia + 1 - ii);
  if (lob > 0)  dmin = min(dmin, jj - lob + 1);
  if (hib < 15) dmin = min(dmin, hib + 1 - jj);
  if (loc > 0)  dmin = min(dmin, kkc - loc + 1);
  if (hic < 15) dmin = min(dmin, hic + 1 - kkc);
  float bnd = ((float)dmin - 0.5f) * (2.0f / 15.0f) - 1e-5f;
  ULL ubk = ((ULL)(__float_as_uint(bnd * bnd) | 0x80000000u)) << 32;
  if (w7 >= ubk) {
#pragma unroll
    for (int q = 0; q < 8; ++q) kk[q] = ~0ULL;
    for (int t = sub; t < 1331; t += 32) {
      int dz = t / 121, r = t - dz * 121;
      int a = ii + dz - 5, c1 = jj + (r / 11) - 5, c2 = kkc + (r % 11) - 5;
      if (((unsigned)a > 15u) | ((unsigned)c1 > 15u) | ((unsigned)c2 > 15u)) continue;
      scan_cell(cs, sp, (a * 16 + c1) * 16 + c2, gx, gy, gz, gn, kk);
    }
    win = merge32(kk, sub);
    float bnd5 = 5.5f * (2.0f / 15.0f) - 1e-5f;
    ULL ub5 = ((ULL)(__float_as_uint(bnd5 * bnd5) | 0x80000000u)) << 32;
    w7 = __shfl(win, (lane & 32) | 7, 64);
    if (w7 >= ub5) {
#pragma unroll
      for (int q = 0; q < 8; ++q) kk[q] = ~0ULL;
      for (int p = sub; p < NP; p += 32) ins8(kk, mkkey(sp[p], gx, gy, gz, gn));
      win = merge32(kk, sub);
    }
  }
  if (sub < 8) idxo[(((b << 12) | g) << 3) + sub] = (int)(win & 0xFFFFFFFFULL);
}

// ------------------------- fused bipartite conv + update MLP via MFMA (bf16x3)
__global__ __launch_bounds__(256) void k_mlp2(
    const float* __restrict__ pos, const float* __restrict__ xf,
    const float* __restrict__ w1, const float* __restrict__ b1,
    const float* __restrict__ b2v, const float* __restrict__ fw,
    const float* __restrict__ fb, const float* __restrict__ ub,
    const ush* __restrict__ w2tH, const ush* __restrict__ w2tL,
    const ush* __restrict__ uwtH, const ush* __restrict__ uwtL,
    const int* __restrict__ idx, float* __restrict__ vol0,
    ush* __restrict__ v0h, ush* __restrict__ v0l) {
  __shared__ __align__(16) ush lhH[128 * 72];
  __shared__ __align__(16) ush lhL[128 * 72];
  __shared__ __align__(16) float lfe[128 * 68];
  __shared__ __align__(16) ush agH[16 * 72];
  __shared__ __align__(16) ush agL[16 * 72];
  __shared__ float gpb[128 * 8];
  int tid = threadIdx.x, lane = tid & 63, wv = tid >> 6;
  int lm = lane & 15, quad = lane >> 4;
  int b = blockIdx.x >> 8;
  int g0 = (blockIdx.x & 255) << 4;
  s8v BH[8], BL[8], UH[2], UL[2];
#pragma unroll
  for (int n = 0; n < 4; ++n)
#pragma unroll
    for (int ks = 0; ks < 2; ++ks) {
      int o = ((n * 16 + lm) << 6) + ks * 32 + (quad << 3);
      BH[n * 2 + ks] = *(const s8v*)(w2tH + o);
      BL[n * 2 + ks] = *(const s8v*)(w2tL + o);
    }
#pragma unroll
  for (int ks = 0; ks < 2; ++ks) {
    int o = ((wv * 16 + lm) << 6) + ks * 32 + (quad << 3);
    UH[ks] = *(const s8v*)(uwtH + o);
    UL[ks] = *(const s8v*)(uwtL + o);
  }
  if (tid < 128) {
    int vi = tid >> 3, kp = tid & 7;
    int g = g0 + vi;
    int p = idx[(((b << 12) | g) << 3) + kp];
    const float* pp = pos + (b * NP + p) * 3;
    const float* xp = xf + (b * NP + p) * 3;
    gpb[tid * 8 + 0] = pp[0]; gpb[tid * 8 + 1] = pp[1]; gpb[tid * 8 + 2] = pp[2];
    gpb[tid * 8 + 3] = xp[0]; gpb[tid * 8 + 4] = xp[1]; gpb[tid * 8 + 5] = xp[2];
  }
  float w10 = w1[lane], w11 = w1[64 + lane], w12 = w1[128 + lane], b1c = b1[lane];
  float fw0 = fw[lane], fw1 = fw[64 + lane], fw2 = fw[128 + lane], fbc = fb[lane];
  float ubc = ub[wv * 16 + lm];
  float gx = lin16(g0 >> 8), gy = lin16((g0 >> 4) & 15);
  __syncthreads();
  for (int i = 0; i < 32; ++i) {
    int pair = wv * 32 + i;
    int vi = pair >> 3;
    float gz = lin16(vi);
    float r0 = gpb[pair * 8 + 0] - gx, r1 = gpb[pair * 8 + 1] - gy, r2 = gpb[pair * 8 + 2] - gz;
    float h1 = gelu_tanh(fmaf(r2, w12, fmaf(r1, w11, fmaf(r0, w10, b1c))));
    float fe = fmaf(gpb[pair * 8 + 5], fw2,
                    fmaf(gpb[pair * 8 + 4], fw1, fmaf(gpb[pair * 8 + 3], fw0, fbc)));
    ush hi = f2bf(h1);
    lhH[pair * 72 + lane] = hi;
    lhL[pair * 72 + lane] = f2bf(h1 - bf2f(hi));
    lfe[pair * 68 + lane] = fe;
  }
  f4v acc[2][4];
#pragma unroll
  for (int m = 0; m < 2; ++m)
#pragma unroll
    for (int n = 0; n < 4; ++n) acc[m][n] = (f4v){0.f, 0.f, 0.f, 0.f};
#pragma unroll
  for (int m = 0; m < 2; ++m)
#pragma unroll
    for (int ks = 0; ks < 2; ++ks) {
      int ao = (wv * 32 + m * 16 + lm) * 72 + ks * 32 + quad * 8;
      s8v Ah = *(const s8v*)&lhH[ao];
      s8v Al = *(const s8v*)&lhL[ao];
#pragma unroll
      for (int n = 0; n < 4; ++n) {
        acc[m][n] = __builtin_amdgcn_mfma_f32_16x16x32_bf16(Ah, BH[n * 2 + ks], acc[m][n], 0, 0, 0);
        acc[m][n] = __builtin_amdgcn_mfma_f32_16x16x32_bf16(Ah, BL[n * 2 + ks], acc[m][n], 0, 0, 0);
        acc[m][n] = __builtin_amdgcn_mfma_f32_16x16x32_bf16(Al, BH[n * 2 + ks], acc[m][n], 0, 0, 0);
      }
    }
  float b2c[4];
#pragma unroll
  for (int n = 0; n < 4; ++n) b2c[n] = b2v[n * 16 + lm];
#pragma unroll
  for (int m = 0; m < 2; ++m) {
    int vox = wv * 4 + m * 2 + (quad >> 1);
#pragma unroll
    for (int n = 0; n < 4; ++n) {
      float s = 0.0f;
#pragma unroll
      for (int r = 0; r < 4; ++r) {
        int pair = wv * 32 + m * 16 + quad * 4 + r;
        s += (acc[m][n][r] + b2c[n]) * lfe[pair * 68 + n * 16 + lm];
      }
      s += __shfl_xor(s, 16, 64);
      s *= 0.125f;
      if ((quad & 1) == 0) {
        ush hi = f2bf(s);
        agH[vox * 72 + n * 16 + lm] = hi;
        agL[vox * 72 + n * 16 + lm] = f2bf(s - bf2f(hi));
      }
    }
  }
  __syncthreads();
  f4v a2 = (f4v){0.f, 0.f, 0.f, 0.f};
#pragma unroll
  for (int ks = 0; ks < 2; ++ks) {
    int ao = lm * 72 + ks * 32 + quad * 8;
    s8v Ah = *(const s8v*)&agH[ao];
    s8v Al = *(const s8v*)&agL[ao];
    a2 = __builtin_amdgcn_mfma_f32_16x16x32_bf16(Ah, UH[ks], a2, 0, 0, 0);
    a2 = __builtin_amdgcn_mfma_f32_16x16x32_bf16(Ah, UL[ks], a2, 0, 0, 0);
    a2 = __builtin_amdgcn_mfma_f32_16x16x32_bf16(Al, UH[ks], a2, 0, 0, 0);
  }
  int xc = g0 >> 8, yc = (g0 >> 4) & 15;
#pragma unroll
  for (int r = 0; r < 4; ++r) {
    int vox = quad * 4 + r;
    float h = gelu_tanh(a2[r] + ubc);
    int pidx = (((b * 18 + vox + 1) * 18 + yc + 1) * 18 + xc + 1) * 64 + wv * 16 + lm;
    vol0[pidx] = h;
    ush hi = f2bf(h);
    v0h[pidx] = hi;
    v0l[pidx] = f2bf(h - bf2f(hi));
  }
}

// ------------- MFMA implicit-GEMM 3x3x3 conv, 64 voxels/block, B-prefetch.
// FUSED=1: stage from fp32 t + BN stats (fused bn+relu+bf16-split); FUSED=0:
// stage from pre-split bf16 hi/lo padded volume.
template <int Z, int FUSED>
__global__ __launch_bounds__(256) void k_convm(const ush* __restrict__ vh,
                                               const ush* __restrict__ vl,
                                               const float* __restrict__ tin,
                                               const float* __restrict__ instats,
                                               float inv_cnt,
                                               const ush* __restrict__ wtH,
                                               const ush* __restrict__ wtL,
                                               float* __restrict__ out,
                                               float* __restrict__ stats) {
  constexpr int P = Z + 2;
  constexpr int Py = (Z == 16) ? 6 : 10;
  constexpr int Px = (Z == 16) ? 18 : 10;
  constexpr int NV = 3 * Py * Px;              // 324 / 300
  constexpr int VS = 272;
  __shared__ unsigned char slab[NV * VS];
  __shared__ float ls[64], ls2[64];
  int tid = threadIdx.x;
  int lane = tid & 63, wv = tid >> 6;
  int vbase = blockIdx.x * 64;
  int b = (Z == 16) ? (vbase >> 12) : (vbase >> 9);
  int rem = vbase & (Z * Z * Z - 1);
  int z0 = rem / (Z * Z);
  int y0 = (Z == 16) ? ((rem & 255) >> 4) : 0;
  if (tid < 64) { ls[tid] = 0.0f; ls2[tid] = 0.0f; }
  if (FUSED) {
    float mreg[8], rreg[8];
    int cb = (tid & 7) * 8;
#pragma unroll
    for (int e = 0; e < 8; ++e) {
      float sm = instats[(cb + e) * 2];
      float sq = instats[(cb + e) * 2 + 1];
      float m = sm * inv_cnt;
      float var = sq * inv_cnt - m * m;
      mreg[e] = m;
      rreg[e] = 1.0f / sqrtf(var + EPSF);
    }
    for (int i = tid; i < NV * 8; i += 256) {
      int v = i >> 3, c = i & 7;
      int lz = v / (Py * Px);
      int r = v - lz * (Py * Px);
      int ly = r / Px, lx = r - ly * Px;
      int rz = z0 + lz - 1, ry = y0 + ly - 1, rx = lx - 1;
      bool ok = ((unsigned)rz < (unsigned)Z) & ((unsigned)ry < (unsigned)Z) &
                ((unsigned)rx < (unsigned)Z);
      float vv[8];
#pragma unroll
      for (int e = 0; e < 8; ++e) vv[e] = 0.0f;
      if (ok) {
        const float* tp = tin + ((((b * Z + rz) * Z + ry) * Z + rx) << 6) + c * 8;
        float4 f0 = *(const float4*)tp;
        float4 f1 = *(const float4*)(tp + 4);
        vv[0] = f0.x; vv[1] = f0.y; vv[2] = f0.z; vv[3] = f0.w;
        vv[4] = f1.x; vv[5] = f1.y; vv[6] = f1.z; vv[7] = f1.w;
      }
      union { ush u[8]; uint4 q; } ph, pq;
#pragma unroll
      for (int e = 0; e < 8; ++e) {
        float x = (vv[e] - mreg[e]) * rreg[e];
        x = (ok && x > 0.0f) ? x : 0.0f;
        ush h = f2bf(x);
        ph.u[e] = h;
        pq.u[e] = f2bf(x - bf2f(h));
      }
      *(uint4*)(slab + v * VS + c * 16) = ph.q;
      *(uint4*)(slab + v * VS + 128 + c * 16) = pq.q;
    }
  } else {
    for (int i = tid; i < NV * 8; i += 256) {
      int v = i >> 3, c = i & 7;
      int lz = v / (Py * Px);
      int r = v - lz * (Py * Px);
      int ly = r / Px, lx = r - ly * Px;
      int g = (((b * P + z0 + lz) * P + (y0 + ly)) * P + lx) * 64 + c * 8;
      *(uint4*)(slab + v * VS + c * 16)       = *(const uint4*)(vh + g);
      *(uint4*)(slab + v * VS + 128 + c * 16) = *(const uint4*)(vl + g);
    }
  }
  __syncthreads();
  int lm = lane & 15, quad = lane >> 4;
  int co = (wv << 4) | lm;
  const ush* bH = wtH + (co << 6) + (quad << 3);   // off stride = 4096 ush
  const ush* bL = wtL + (co << 6) + (quad << 3);
  s8v cH0 = *(const s8v*)(bH), cH1 = *(const s8v*)(bH + 32);
  s8v cL0 = *(const s8v*)(bL), cL1 = *(const s8v*)(bL + 32);
  f4v acc[4];
#pragma unroll
  for (int m = 0; m < 4; ++m) acc[m] = (f4v){0.f, 0.f, 0.f, 0.f};
  for (int off = 0; off < 27; ++off) {
    int noff = (off < 26) ? off + 1 : 26;          // prefetch next B-frags
    const ush* nbH = bH + noff * 4096;
    const ush* nbL = bL + noff * 4096;
    s8v nH0 = *(const s8v*)(nbH), nH1 = *(const s8v*)(nbH + 32);
    s8v nL0 = *(const s8v*)(nbL), nL1 = *(const s8v*)(nbL + 32);
    int dz = off / 9, r9 = off - dz * 9, dy = r9 / 3, dx = r9 - dy * 3;
#pragma unroll
    for (int ks = 0; ks < 2; ++ks) {
      s8v bhf = ks ? cH1 : cH0;
      s8v blf = ks ? cL1 : cL0;
#pragma unroll
      for (int m = 0; m < 4; ++m) {
        int lyp, lxp;
        if (Z == 16) { lyp = m + dy; lxp = lm + dx; }
        else         { lyp = 2 * m + (lm >> 3) + dy; lxp = (lm & 7) + dx; }
        int sv = (dz * Py + lyp) * Px + lxp;
        const unsigned char* ap = slab + sv * VS + (quad << 4) + (ks << 6);
        s8v ahf = *(const s8v*)(ap);
        s8v alf = *(const s8v*)(ap + 128);
        acc[m] = __builtin_amdgcn_mfma_f32_16x16x32_bf16(ahf, bhf, acc[m], 0, 0, 0);
        acc[m] = __builtin_amdgcn_mfma_f32_16x16x32_bf16(ahf, blf, acc[m], 0, 0, 0);
        acc[m] = __builtin_amdgcn_mfma_f32_16x16x32_bf16(alf, bhf, acc[m], 0, 0, 0);
      }
    }
    cH0 = nH0; cH1 = nH1; cL0 = nL0; cL1 = nL1;
  }
  float s = 0.0f, s2 = 0.0f;
#pragma unroll
  for (int m = 0; m < 4; ++m) {
    int vx = vbase + (m << 4) + (quad << 2);
#pragma unroll
    for (int r = 0; r < 4; ++r) {
      float v = acc[m][r];
      out[(vx + r) * 64 + co] = v;
      s += v;
      s2 = fmaf(v, v, s2);
    }
  }
  atomicAdd(&ls[co], s);
  atomicAdd(&ls2[co], s2);
  __syncthreads();
  if (tid < 64) {
    atomicAdd(&stats[tid * 2], ls[tid]);
    atomicAdd(&stats[tid * 2 + 1], ls2[tid]);
  }
}

// --------------------------------- vol = relu(vol0 + bn(t2)) then 2x2x2 maxpool
__global__ __launch_bounds__(256) void k_residpool(const float* __restrict__ vol0,
                                                   const float* __restrict__ t2,
                                                   const float* __restrict__ stats,
                                                   float* __restrict__ vol1,
                                                   ush* __restrict__ v1h,
                                                   ush* __restrict__ v1l) {
  unsigned i = blockIdx.x * 256u + threadIdx.x;
  int c = i & 63;
  int pv = i >> 6;
  int xp = pv & 7, yp = (pv >> 3) & 7, zp = (pv >> 6) & 7, b = pv >> 9;
  float m = stats[c * 2] * (1.0f / 16384.0f);
  float var = stats[c * 2 + 1] * (1.0f / 16384.0f) - m * m;
  float rs = 1.0f / sqrtf(var + EPSF);
  float best = 0.0f;
  for (int dz = 0; dz < 2; ++dz)
    for (int dy = 0; dy < 2; ++dy)
      for (int dx = 0; dx < 2; ++dx) {
        int z = 2 * zp + dz, y = 2 * yp + dy, x = 2 * xp + dx;
        float a = vol0[(((b * 18 + z + 1) * 18 + y + 1) * 18 + x + 1) * 64 + c];
        float t = t2[(b * 4096 + z * 256 + y * 16 + x) * 64 + c];
        float u = a + (t - m) * rs;
        u = u > 0.0f ? u : 0.0f;
        best = u > best ? u : best;
      }
  int pidx = (((b * 10 + zp + 1) * 10 + yp + 1) * 10 + xp + 1) * 64 + c;
  vol1[pidx] = best;
  ush hi = f2bf(best);
  v1h[pidx] = hi;
  v1l[pidx] = f2bf(best - bf2f(hi));
}

// -------------------- vol2 = relu(vol1 + bn(t4)); only its BN stats are needed
__global__ __launch_bounds__(256) void k_resid2(const float* __restrict__ vol1,
                                                const float* __restrict__ t4,
                                                const float* __restrict__ stats,
                                                float* __restrict__ sF,
                                                float* __restrict__ sB) {
  __shared__ float ls[64], ls2[64];
  if (threadIdx.x < 64) { ls[threadIdx.x] = 0.0f; ls2[threadIdx.x] = 0.0f; }
  __syncthreads();
  unsigned i = blockIdx.x * 256u + threadIdx.x;
  int c = i & 63;
  int pv = i >> 6;
  int x = pv & 7, y = (pv >> 3) & 7, z = (pv >> 6) & 7, b = pv >> 9;
  float m = stats[c * 2] * (1.0f / 2048.0f);
  float var = stats[c * 2 + 1] * (1.0f / 2048.0f) - m * m;
  float rs = 1.0f / sqrtf(var + EPSF);
  float a = vol1[(((b * 10 + z + 1) * 10 + y + 1) * 10 + x + 1) * 64 + c];
  float u = a + (t4[i] - m) * rs;
  u = u > 0.0f ? u : 0.0f;
  atomicAdd(&ls[c], u);
  atomicAdd(&ls2[c], u * u);
  __syncthreads();
  if (threadIdx.x < 64) {
    int cc = threadIdx.x;
    atomicAdd(&sF[cc * 2], ls[cc]);
    atomicAdd(&sF[cc * 2 + 1], ls2[cc]);
    atomicAdd(&sB[b * 64 + cc], ls[cc]);
  }
}

// ------------- final bn affine + spatial mean pool + linear head -> [4,16]
__global__ __launch_bounds__(64) void k_final(const float* __restrict__ sF,
                                              const float* __restrict__ sB,
                                              const float* __restrict__ ong,
                                              const float* __restrict__ onb,
                                              const float* __restrict__ row,
                                              const float* __restrict__ rob,
                                              float* __restrict__ outp) {
  __shared__ float pl[4][64];
  int c = threadIdx.x;
  float m = sF[c * 2] * (1.0f / 2048.0f);
  float var = sF[c * 2 + 1] * (1.0f / 2048.0f) - m * m;
  float rs = 1.0f / sqrtf(var + EPSF);
  float gg = ong[c], bb = onb[c];
  for (int b = 0; b < 4; ++b)
    pl[b][c] = (sB[b * 64 + c] * (1.0f / 512.0f) - m) * rs * gg + bb;
  __syncthreads();
  int b = threadIdx.x >> 4, o = threadIdx.x & 15;
  float s = rob[o];
  for (int j = 0; j < 64; ++j) s = fmaf(pl[b][j], row[j * 16 + o], s);
  outp[b * 16 + o] = s;
}

extern "C" void kernel_launch(void* const* d_in, const int* in_sizes, int n_in,
                              void* d_out, int out_size, void* d_ws, size_t ws_size,
                              hipStream_t stream) {
  (void)in_sizes; (void)n_in; (void)out_size; (void)ws_size;
  const float* pos = (const float*)d_in[0];
  const float* xf  = (const float*)d_in[1];
  const float* pw1 = (const float*)d_in[2];
  const float* pb1 = (const float*)d_in[3];
  const float* pw2 = (const float*)d_in[4];
  const float* pb2 = (const float*)d_in[5];
  const float* fw  = (const float*)d_in[6];
  const float* fb  = (const float*)d_in[7];
  const float* uw  = (const float*)d_in[8];
  const float* ubp = (const float*)d_in[9];
  const float* cw  = (const float*)d_in[10];
  // d_in[11] = conv_b: unused (training-mode BN cancels conv bias exactly)
  const float* ong = (const float*)d_in[12];
  const float* onb = (const float*)d_in[13];
  const float* row = (const float*)d_in[14];
  const float* rob = (const float*)d_in[15];

  float* ws   = (float*)d_ws;
  ush*   wh   = (ush*)(ws + WH_OFF);
  ush*   wl   = (ush*)(ws + WL_OFF);
  int*   idx  = (int*)(ws + IDX_OFF);
  float* vol0 = ws + VOL0_OFF;
  ush*   v0h  = (ush*)(ws + V0H_OFF);
  ush*   v0l  = (ush*)(ws + V0L_OFF);
  float* t1   = ws + T1_OFF;
  float* t2   = ws + V0H_OFF;          // reuses v0h/v0l region (consumed by conv1)
  float* vol1 = ws + VOL1_OFF;
  ush*   v1h  = (ush*)(ws + V1H_OFF);
  ush*   v1l  = (ush*)(ws + V1L_OFF);
  float* t3   = ws + T3_OFF;
  float* t4   = ws + V1H_OFF;          // reuses v1h/v1l region (consumed by conv3)
  float* sA   = ws + STATS_OFF;
  float* sF   = sA + 512;
  float* sB   = sF + 128;
  int*   cellStart = (int*)(ws + CELLS_OFF);
  float4* sortedPos = (float4*)(ws + SPOS_OFF);
  ush*   mw   = (ush*)(ws + MW_OFF);

  k_prepbin<<<1764, 256, 0, stream>>>(cw, pw2, uw, pos, wh, wl, mw, ws,
                                      cellStart, sortedPos);
  k_knn5<<<2048, 256, 0, stream>>>(cellStart, sortedPos, idx);
  k_mlp2<<<1024, 256, 0, stream>>>(pos, xf, pw1, pb1, pb2, fw, fb, ubp,
                                   mw, mw + 4096, mw + 8192, mw + 12288,
                                   idx, vol0, v0h, v0l);
  // block 0 (16^3): conv1 (bf16 staging) -> conv2 (fused bn+relu staging from t1)
  k_convm<16, 0><<<256, 256, 0, stream>>>(v0h, v0l, nullptr, nullptr, 0.0f,
                                          wh, wl, t1, sA);
  k_convm<16, 1><<<256, 256, 0, stream>>>(nullptr, nullptr, t1, sA, 1.0f / 16384.0f,
                                          wh + WT_PER_CONV, wl + WT_PER_CONV,
                                          t2, sA + 128);
  k_residpool<<<512, 256, 0, stream>>>(vol0, t2, sA + 128, vol1, v1h, v1l);
  // block 1 (8^3): conv3 (bf16 staging) -> conv4 (fused bn+relu staging from t3)
  k_convm<8, 0><<<32, 256, 0, stream>>>(v1h, v1l, nullptr, nullptr, 0.0f,
                                        wh + 2 * WT_PER_CONV, wl + 2 * WT_PER_CONV,
                                        t3, sA + 256);
  k_convm<8, 1><<<32, 256, 0, stream>>>(nullptr, nullptr, t3, sA + 256, 1.0f / 2048.0f,
                                        wh + 3 * WT_PER_CONV, wl + 3 * WT_PER_CONV,
                                        t4, sA + 384);
  k_resid2<<<512, 256, 0, stream>>>(vol1, t4, sA + 384, sF, sB);
  // head
  k_final<<<1, 64, 0, stream>>>(sF, sB, ong, onb, row, rob, (float*)d_out);
}